// Round 7
// baseline (770.274 us; speedup 1.0000x reference)
//
#include <hip/hip_runtime.h>
#include <stdint.h>

#define NN 50000
#define CC 1024
#define HH 128
#define EE 1600000
#define EPSV 1e-8f
#define SCAN_BLKS 196   // ceil(50000/256)

typedef __attribute__((ext_vector_type(8))) short bf16x8;
typedef __attribute__((ext_vector_type(4))) float f32x4;
typedef __attribute__((ext_vector_type(2))) float f32x2;

__device__ __forceinline__ unsigned short f32_to_bf16(float f){
  union { float f; uint32_t u; } cv; cv.f = f;
  uint32_t u = cv.u;
  return (unsigned short)((u + 0x7FFFu + ((u >> 16) & 1u)) >> 16);
}
__device__ __forceinline__ float bf16lo_to_f32(uint32_t w){
  union { uint32_t u; float f; } cv; cv.u = w << 16; return cv.f;
}
__device__ __forceinline__ float bf16hi_to_f32(uint32_t w){
  union { uint32_t u; float f; } cv; cv.u = w & 0xFFFF0000u; return cv.f;
}

// DPP cross-lane add within a 16-lane row (xor1, xor2, ^7-in-8, ^15-in-16)
#define DPP_ADD(x, ctrl) ((x) + __int_as_float(__builtin_amdgcn_update_dpp(0, __float_as_int(x), (ctrl), 0xF, 0xF, true)))

// ---------------- prep kernels ----------------

__global__ __launch_bounds__(256) void k_prep_w1t(const float* __restrict__ W1,
                                                  unsigned short* __restrict__ W1T){
  int idx = blockIdx.x*256 + threadIdx.x;          // 128*1024, W1T[n][k]
  if(idx >= 128*1024) return;
  int n = idx >> 10, k = idx & 1023;
  W1T[idx] = f32_to_bf16(W1[k*128 + n]);
}

__global__ __launch_bounds__(256) void k_prep_w2t(const float* __restrict__ W2,
                                                  unsigned short* __restrict__ W2T){
  int idx = blockIdx.x*256 + threadIdx.x;          // 128*128, W2T[n][k]
  if(idx >= 128*128) return;
  int n = idx >> 7, k = idx & 127;
  W2T[idx] = f32_to_bf16(W2[k*128 + n]);
}

// Wg1T[c][k], c in [0,256): c<128 -> u-col uses Wg1[k][c]; c>=128 -> v-col uses Wg1[128+k][c-128]
__global__ __launch_bounds__(256) void k_prep_wg1T(const float* __restrict__ Wg1,
                                                   unsigned short* __restrict__ T){
  int idx = blockIdx.x*256 + threadIdx.x;          // 256*128
  if(idx >= 256*128) return;
  int c = idx >> 7, k = idx & 127;
  int row = (c < 128) ? k : (128 + k);
  int col = (c < 128) ? c : (c - 128);
  T[idx] = f32_to_bf16(Wg1[row*128 + col]);
}

// ---------------- CSR build: hist + 3-kernel parallel scan + fill ----------------

__global__ __launch_bounds__(256) void k_hist(const int* __restrict__ dst,
                                              int* __restrict__ counts){
  int e = blockIdx.x*256 + threadIdx.x;
  if(e < EE) atomicAdd(&counts[dst[e]], 1);
}

__global__ __launch_bounds__(256) void k_scan1(const int* __restrict__ counts,
    int* __restrict__ lexcl, int* __restrict__ bsum){
  __shared__ int buf[256];
  const int t = threadIdx.x, i = blockIdx.x*256 + t;
  int v = (i < NN) ? counts[i] : 0;
  buf[t] = v;
  __syncthreads();
  for(int off = 1; off < 256; off <<= 1){
    int add = (t >= off) ? buf[t-off] : 0;
    __syncthreads();
    buf[t] += add;
    __syncthreads();
  }
  if(i < NN) lexcl[i] = buf[t] - v;
  if(t == 255) bsum[blockIdx.x] = buf[255];
}

__global__ __launch_bounds__(256) void k_scan2(const int* __restrict__ bsum,
    int* __restrict__ bexcl, int* __restrict__ row_ptr){
  __shared__ int buf[256];
  const int t = threadIdx.x;
  int v = (t < SCAN_BLKS) ? bsum[t] : 0;
  buf[t] = v;
  __syncthreads();
  for(int off = 1; off < 256; off <<= 1){
    int add = (t >= off) ? buf[t-off] : 0;
    __syncthreads();
    buf[t] += add;
    __syncthreads();
  }
  if(t < SCAN_BLKS) bexcl[t] = buf[t] - v;
  if(t == 255) row_ptr[NN] = buf[255];
}

__global__ __launch_bounds__(256) void k_scan3(const int* __restrict__ lexcl,
    const int* __restrict__ bexcl, int* __restrict__ row_ptr, int* __restrict__ cursor){
  const int i = blockIdx.x*256 + threadIdx.x;
  if(i >= NN) return;
  int e = lexcl[i] + bexcl[blockIdx.x];
  row_ptr[i] = e;
  cursor[i]  = e;
}

// fill CSR slots; computes c = base_w*sig(rho_src)*sig(rho_dst) inline into permuted order
__global__ __launch_bounds__(256) void k_fill(const int* __restrict__ src,
    const int* __restrict__ dst, const float* __restrict__ base_w,
    const float* __restrict__ rho_raw, int* __restrict__ cursor,
    int* __restrict__ src_perm, float* __restrict__ c_perm){
  int e = blockIdx.x*256 + threadIdx.x;
  if(e >= EE) return;
  int s = src[e], d = dst[e];
  int p = atomicAdd(&cursor[d], 1);
  float rs = 1.f/(1.f + __expf(-rho_raw[s]));
  float rd = 1.f/(1.f + __expf(-rho_raw[d]));
  src_perm[p] = s;
  c_perm[p]   = base_w[e]*rs*rd;
}

// ---------------- encoder GEMM1: h1 = relu(X@W1 + b1) -> bf16 [N,128] ----------------
// Double-buffered LDS + DEPTH-2 register prefetch: tile k+2's global loads issue at
// step k, are ds_written at end of step k+1 (~1.7 K-steps of latency budget).

__global__ __launch_bounds__(256) void k_enc1(
    const float* __restrict__ X, const unsigned short* __restrict__ W1T,
    const float* __restrict__ b1, unsigned short* __restrict__ h1)
{
  __shared__ __attribute__((aligned(16))) unsigned short As[2][64*40];
  __shared__ __attribute__((aligned(16))) unsigned short Bs[2][128*40];

  const int t = threadIdx.x, w = t >> 6, lane = t & 63;
  const int rowL = lane & 15, kq = lane >> 4;
  const int wm = w >> 1, wn = w & 1;
  const int row0 = blockIdx.x * 64;

  const int arow = t >> 2, ac8  = (t & 3) * 8;
  const int brow = t >> 1, bk16 = (t & 1) * 16;
  int ag = row0 + arow; if(ag >= NN) ag = NN - 1;
  const float* xp = X + (size_t)ag*1024 + ac8;
  const unsigned short* wp = W1T + (size_t)brow*1024 + bk16;

  f32x4 ra0[2], ra1[2]; bf16x8 rb0[2], rb1[2];
  ra0[0] = *(const f32x4*)(xp);       ra1[0] = *(const f32x4*)(xp + 4);
  rb0[0] = *(const bf16x8*)(wp);      rb1[0] = *(const bf16x8*)(wp + 8);
  ra0[1] = *(const f32x4*)(xp + 32);  ra1[1] = *(const f32x4*)(xp + 36);
  rb0[1] = *(const bf16x8*)(wp + 32); rb1[1] = *(const bf16x8*)(wp + 40);

  { // stage tile 0
    union { bf16x8 v; unsigned short s[8]; } pk;
    #pragma unroll
    for(int j = 0; j < 4; j++){ pk.s[j] = f32_to_bf16(ra0[0][j]); pk.s[4+j] = f32_to_bf16(ra1[0][j]); }
    *(bf16x8*)&As[0][arow*40 + ac8] = pk.v;
    *(bf16x8*)&Bs[0][brow*40 + bk16]     = rb0[0];
    *(bf16x8*)&Bs[0][brow*40 + bk16 + 8] = rb1[0];
  }
  __syncthreads();

  f32x4 acc[2][4] = {};
  for(int k = 0; k < 32; k++){
    const int cur = k & 1, nxt = cur ^ 1;
    if(k < 30){                                  // issue tile k+2 into the freed slot
      const int ko = (k + 2) * 32;
      ra0[cur] = *(const f32x4*)(xp + ko);
      ra1[cur] = *(const f32x4*)(xp + ko + 4);
      rb0[cur] = *(const bf16x8*)(wp + ko);
      rb1[cur] = *(const bf16x8*)(wp + ko + 8);
    }
    // compute tile k from LDS[cur]
    bf16x8 af[2], bfr[4];
    #pragma unroll
    for(int mf = 0; mf < 2; mf++)
      af[mf] = *(const bf16x8*)&As[cur][(wm*32 + mf*16 + rowL)*40 + kq*8];
    #pragma unroll
    for(int nf = 0; nf < 4; nf++)
      bfr[nf] = *(const bf16x8*)&Bs[cur][(wn*64 + nf*16 + rowL)*40 + kq*8];
    #pragma unroll
    for(int mf = 0; mf < 2; mf++)
      #pragma unroll
      for(int nf = 0; nf < 4; nf++)
        acc[mf][nf] = __builtin_amdgcn_mfma_f32_16x16x32_bf16(af[mf], bfr[nf], acc[mf][nf], 0, 0, 0);
    if(k < 31){                                  // stage tile k+1 (loaded one step ago)
      union { bf16x8 v; unsigned short s[8]; } pk;
      #pragma unroll
      for(int j = 0; j < 4; j++){ pk.s[j] = f32_to_bf16(ra0[nxt][j]); pk.s[4+j] = f32_to_bf16(ra1[nxt][j]); }
      *(bf16x8*)&As[nxt][arow*40 + ac8] = pk.v;
      *(bf16x8*)&Bs[nxt][brow*40 + bk16]     = rb0[nxt];
      *(bf16x8*)&Bs[nxt][brow*40 + bk16 + 8] = rb1[nxt];
    }
    __syncthreads();
  }

  // epilogue: bias + relu + bf16 store. C frag: row = kq*4+r, col = rowL.
  #pragma unroll
  for(int mf = 0; mf < 2; mf++){
    #pragma unroll
    for(int nf = 0; nf < 4; nf++){
      const int col = wn*64 + nf*16 + rowL;
      const float bv = b1[col];
      #pragma unroll
      for(int r = 0; r < 4; r++){
        const int gr = row0 + wm*32 + mf*16 + kq*4 + r;
        if(gr < NN) h1[(size_t)gr*128 + col] = f32_to_bf16(fmaxf(acc[mf][nf][r] + bv, 0.f));
      }
    }
  }
}

// ---------------- shared UV phase: [u|v] = h @ Wg1T from swizzled LDS h ----------------
// hs: 64 rows x 128 bf16, chunk c of row r stored at chunk (c ^ (r&15)).

__device__ __forceinline__ void uv_phase2(
    const unsigned short* hs, int row0, int wave, int lane,
    const unsigned short* __restrict__ Wg1T, const float* __restrict__ bg1,
    unsigned short* __restrict__ UH, float* __restrict__ Vf)
{
  const int rowL = lane & 15, kq = lane >> 4;
  const int r = wave*16 + rowL;                      // A row (local)
  f32x4 acc[16] = {};
  #pragma unroll
  for(int ks = 0; ks < 4; ks++){
    const int kc = ks*4 + kq;
    bf16x8 a = *(const bf16x8*)&hs[r*128 + ((kc ^ (r & 15)) << 3)];
    #pragma unroll
    for(int nt = 0; nt < 16; nt++){
      bf16x8 b = *(const bf16x8*)(Wg1T + (size_t)(nt*16 + rowL)*128 + ks*32 + kq*8);
      acc[nt] = __builtin_amdgcn_mfma_f32_16x16x32_bf16(a, b, acc[nt], 0, 0, 0);
    }
  }
  #pragma unroll
  for(int nt = 0; nt < 16; nt++){
    const int col = nt*16 + rowL;
    #pragma unroll
    for(int rr = 0; rr < 4; rr++){
      const int gr = row0 + wave*16 + kq*4 + rr;
      if(gr < NN){
        if(col < 128) UH[(size_t)gr*256 + col] = f32_to_bf16(acc[nt][rr]);
        else          Vf[(size_t)gr*128 + col - 128] = acc[nt][rr] + bg1[col - 128];
      }
    }
  }
}

// ---------------- k_uvA: h = relu(h1@W2T + b2); writes UH=[u|h] bf16, Vf=v+bg1 ----------------

__global__ __launch_bounds__(256) void k_uvA(
    const unsigned short* __restrict__ h1, const unsigned short* __restrict__ W2T,
    const float* __restrict__ b2, const unsigned short* __restrict__ Wg1T,
    const float* __restrict__ bg1, unsigned short* __restrict__ UH,
    float* __restrict__ Vf)
{
  __shared__ __attribute__((aligned(16))) unsigned short hs[64*128];
  const int t = threadIdx.x, wave = t >> 6, lane = t & 63;
  const int rowL = lane & 15, kq = lane >> 4;
  const int row0 = blockIdx.x*64;

  // phase 1: h = relu(h1 @ W2T + b2); A direct from global h1, B from L2-resident W2T
  int ar = row0 + wave*16 + rowL; if(ar >= NN) ar = NN-1;
  f32x4 acc[8] = {};
  #pragma unroll
  for(int ks = 0; ks < 4; ks++){
    bf16x8 a = *(const bf16x8*)(h1 + (size_t)ar*128 + ks*32 + kq*8);
    #pragma unroll
    for(int nt = 0; nt < 8; nt++){
      bf16x8 b = *(const bf16x8*)(W2T + (nt*16 + rowL)*128 + ks*32 + kq*8);
      acc[nt] = __builtin_amdgcn_mfma_f32_16x16x32_bf16(a, b, acc[nt], 0, 0, 0);
    }
  }
  // h -> swizzled LDS (bf16 scalars)
  #pragma unroll
  for(int nt = 0; nt < 8; nt++){
    const int col = nt*16 + rowL;
    const float bv = b2[col];
    #pragma unroll
    for(int r = 0; r < 4; r++){
      const int rw = wave*16 + kq*4 + r;
      const unsigned short hv = f32_to_bf16(fmaxf(acc[nt][r] + bv, 0.f));
      hs[rw*128 + (((col >> 3) ^ (rw & 15)) << 3) + (col & 7)] = hv;
    }
  }
  __syncthreads();
  // copy h to UH h-half (coalesced 16B)
  {
    const int r = t >> 2, gr = row0 + r;
    if(gr < NN){
      #pragma unroll
      for(int j8 = 0; j8 < 4; j8++){
        const int chunk = (t & 3)*4 + j8;
        bf16x8 v = *(const bf16x8*)&hs[r*128 + ((chunk ^ (r & 15)) << 3)];
        *(bf16x8*)&UH[(size_t)gr*256 + 128 + chunk*8] = v;
      }
    }
  }
  uv_phase2(hs, row0, wave, lane, Wg1T, bg1, UH, Vf);
}

// ---------------- k_uvB: input h f32 (agg output); writes UH=[u|h] bf16, Vf=v+bg1 ----------------

__global__ __launch_bounds__(256) void k_uvB(
    const float* __restrict__ hf, const unsigned short* __restrict__ Wg1T,
    const float* __restrict__ bg1, unsigned short* __restrict__ UH,
    float* __restrict__ Vf)
{
  __shared__ __attribute__((aligned(16))) unsigned short hs[64*128];
  const int t = threadIdx.x, wave = t >> 6, lane = t & 63;
  const int row0 = blockIdx.x*64;

  {
    const int r = t >> 2, gr0 = row0 + r;
    const int gr = (gr0 < NN) ? gr0 : NN-1;
    const float* p = hf + (size_t)gr*128 + (t & 3)*32;
    #pragma unroll
    for(int j8 = 0; j8 < 4; j8++){
      f32x4 v0 = *(const f32x4*)(p + j8*8);
      f32x4 v1 = *(const f32x4*)(p + j8*8 + 4);
      union { bf16x8 v; unsigned short s[8]; } pk;
      #pragma unroll
      for(int j = 0; j < 4; j++){ pk.s[j] = f32_to_bf16(v0[j]); pk.s[4+j] = f32_to_bf16(v1[j]); }
      const int chunk = (t & 3)*4 + j8;
      *(bf16x8*)&hs[r*128 + ((chunk ^ (r & 15)) << 3)] = pk.v;
      if(gr0 < NN) *(bf16x8*)&UH[(size_t)gr0*256 + 128 + chunk*8] = pk.v;
    }
  }
  __syncthreads();
  uv_phase2(hs, row0, wave, lane & 63, Wg1T, bg1, UH, Vf);
}

// ---------------- fused gate + aggregation, CSR order, one wave per dst node ----------------
// gate: 4 edges/iter, 16 lanes/edge, DPP row reduction, 1-group software pipeline.

__global__ __launch_bounds__(256) void k_gate_agg(
    const unsigned short* __restrict__ UH, const float* __restrict__ Vf,
    const int* __restrict__ row_ptr, const int* __restrict__ src_perm,
    const float* __restrict__ c_perm,
    const float* __restrict__ Wg2, const float* __restrict__ bg2p,
    float* __restrict__ out_f32)
{
  __shared__ float2 ws_s[4][64];
  const int wv = threadIdx.x >> 6, lane = threadIdx.x & 63;
  const int gw = blockIdx.x*4 + wv;
  if(gw >= NN) return;
  const int eq = lane >> 4, li = lane & 15;

  f32x4 va = *(const f32x4*)(Vf + (size_t)gw*128 + li*8);
  f32x4 vb = *(const f32x4*)(Vf + (size_t)gw*128 + li*8 + 4);
  f32x4 wa = *(const f32x4*)(Wg2 + li*8);
  f32x4 wb = *(const f32x4*)(Wg2 + li*8 + 4);
  const float vch[8]  = {va[0],va[1],va[2],va[3],vb[0],vb[1],vb[2],vb[3]};
  const float w2ch[8] = {wa[0],wa[1],wa[2],wa[3],wb[0],wb[1],wb[2],wb[3]};
  const float bg2v = bg2p[0];

  const int beg = row_ptr[gw], end = row_ptr[gw+1];
  float a0 = 0.f, a1 = 0.f, wsum = 0.f;

  for(int base = beg; base < end; base += 64){
    const int nb = min(64, end - base);

    // ---- gate: software-pipelined, 4 edges/iter ----
    int s_c; float cv_c; bf16x8 u_c;
    {
      const int idx = eq, slot = base + ((idx < nb) ? idx : 0);
      s_c = src_perm[slot]; cv_c = c_perm[slot];
      u_c = *(const bf16x8*)&UH[(uint32_t)s_c*256u + li*8];
    }
    for(int q = 0; q < nb; q += 4){
      int s_n = 0; float cv_n = 0.f; bf16x8 u_n = {};
      if(q + 4 < nb){
        const int idx = q + 4 + eq, slot = base + ((idx < nb) ? idx : 0);
        s_n = src_perm[slot]; cv_n = c_perm[slot];
        u_n = *(const bf16x8*)&UH[(uint32_t)s_n*256u + li*8];
      }
      union { bf16x8 v; uint32_t u32[4]; } uu; uu.v = u_c;
      float tacc = 0.f;
      #pragma unroll
      for(int p = 0; p < 4; p++){
        const uint32_t w2b = uu.u32[p];
        tacc += fmaxf(bf16lo_to_f32(w2b) + vch[2*p],   0.f) * w2ch[2*p];
        tacc += fmaxf(bf16hi_to_f32(w2b) + vch[2*p+1], 0.f) * w2ch[2*p+1];
      }
      // DPP reduce over the 16-lane row: xor1, xor2, ^7-in-8, ^15-in-16
      tacc = DPP_ADD(tacc, 0xB1);
      tacc = DPP_ADD(tacc, 0x4E);
      tacc = DPP_ADD(tacc, 0x141);
      tacc = DPP_ADD(tacc, 0x140);
      const float g = 1.f/(1.f + __expf(-(tacc + bg2v)));
      const int idx = q + eq;
      if(li == 0 && idx < nb) ws_s[wv][idx] = make_float2(cv_c*g, __int_as_float(s_c));
      s_c = s_n; cv_c = cv_n; u_c = u_n;
    }

    // ---- aggregate (same-wave LDS producer/consumer; no barrier needed) ----
    #pragma unroll 8
    for(int j = 0; j < nb; j++){
      const float2 p = ws_s[wv][j];
      const float w  = p.x;
      const uint32_t s = (uint32_t)__float_as_int(p.y);
      const uint32_t hw = *(const uint32_t*)&UH[s*256u + 128u + lane*2];
      a0 += w*bf16lo_to_f32(hw);
      a1 += w*bf16hi_to_f32(hw);
      wsum += w;
    }
  }
  const float inv = 1.f/(wsum + EPSV);
  const size_t o = (size_t)gw*128 + lane*2;
  *(f32x2*)&out_f32[o] = (f32x2){a0*inv, a1*inv};
}

// ---------------- launch ----------------

extern "C" void kernel_launch(void* const* d_in, const int* in_sizes, int n_in,
                              void* d_out, int out_size, void* d_ws, size_t ws_size,
                              hipStream_t stream) {
  (void)in_sizes; (void)n_in; (void)out_size; (void)ws_size;
  const float* X      = (const float*)d_in[0];
  const int*   src    = (const int*)d_in[1];
  const int*   dst    = (const int*)d_in[2];
  const float* base_w = (const float*)d_in[3];
  const float* W1     = (const float*)d_in[4];
  const float* b1     = (const float*)d_in[5];
  const float* W2     = (const float*)d_in[6];
  const float* b2     = (const float*)d_in[7];
  const float* Wg1    = (const float*)d_in[8];
  const float* bg1    = (const float*)d_in[9];
  const float* Wg2    = (const float*)d_in[10];
  const float* bg2    = (const float*)d_in[11];
  const float* rho    = (const float*)d_in[12];

  char* ws = (char*)d_ws;
  size_t off = 0;
  auto alloc = [&](size_t bytes)->char*{ char* p = ws + off; off += (bytes + 255) & ~(size_t)255; return p; };
  unsigned short* W1T      = (unsigned short*)alloc((size_t)1024*128*2);
  unsigned short* W2T      = (unsigned short*)alloc((size_t)128*128*2);
  unsigned short* Wg1T     = (unsigned short*)alloc((size_t)256*128*2);
  int*            src_perm = (int*)alloc((size_t)EE*4);
  float*          c_perm   = (float*)alloc((size_t)EE*4);
  int*            row_ptr  = (int*)alloc((size_t)(NN+1)*4);
  int*            cursor   = (int*)alloc((size_t)NN*4);
  int*            counts   = (int*)alloc((size_t)NN*4);
  int*            lexcl    = (int*)alloc((size_t)NN*4);
  int*            bsum     = (int*)alloc((size_t)256*4);
  int*            bexcl    = (int*)alloc((size_t)256*4);
  unsigned short* h1       = (unsigned short*)alloc((size_t)NN*128*2);
  unsigned short* UH       = (unsigned short*)alloc((size_t)NN*256*2);
  float*          Vf       = (float*)alloc((size_t)NN*128*4);
  float*          hf_B     = (float*)alloc((size_t)NN*128*4);

  hipMemsetAsync(counts, 0, (size_t)NN*4, stream);
  k_prep_w1t<<<512, 256, 0, stream>>>(W1, W1T);
  k_prep_w2t<<<64, 256, 0, stream>>>(W2, W2T);
  k_prep_wg1T<<<128, 256, 0, stream>>>(Wg1, Wg1T);
  k_hist<<<EE/256, 256, 0, stream>>>(dst, counts);
  k_scan1<<<SCAN_BLKS, 256, 0, stream>>>(counts, lexcl, bsum);
  k_scan2<<<1, 256, 0, stream>>>(bsum, bexcl, row_ptr);
  k_scan3<<<SCAN_BLKS, 256, 0, stream>>>(lexcl, bexcl, row_ptr, cursor);
  k_fill<<<EE/256, 256, 0, stream>>>(src, dst, base_w, rho, cursor, src_perm, c_perm);

  k_enc1<<<782, 256, 0, stream>>>(X, W1T, b1, h1);

  // layer 1
  k_uvA<<<782, 256, 0, stream>>>(h1, W2T, b2, Wg1T, bg1, UH, Vf);
  k_gate_agg<<<12500, 256, 0, stream>>>(UH, Vf, row_ptr, src_perm, c_perm, Wg2, bg2, hf_B);
  // layer 2
  k_uvB<<<782, 256, 0, stream>>>(hf_B, Wg1T, bg1, UH, Vf);
  k_gate_agg<<<12500, 256, 0, stream>>>(UH, Vf, row_ptr, src_perm, c_perm, Wg2, bg2, (float*)d_out);
}

// Round 8
// 574.239 us; speedup vs baseline: 1.3414x; 1.3414x over previous
//
#include <hip/hip_runtime.h>
#include <stdint.h>

#define NN 50000
#define CC 1024
#define HH 128
#define EE 1600000
#define EPSV 1e-8f
#define SCAN_BLKS 196   // ceil(50000/256)

typedef __attribute__((ext_vector_type(8))) short bf16x8;
typedef __attribute__((ext_vector_type(4))) float f32x4;
typedef __attribute__((ext_vector_type(2))) float f32x2;

__device__ __forceinline__ unsigned short f32_to_bf16(float f){
  union { float f; uint32_t u; } cv; cv.f = f;
  uint32_t u = cv.u;
  return (unsigned short)((u + 0x7FFFu + ((u >> 16) & 1u)) >> 16);
}
__device__ __forceinline__ float bf16lo_to_f32(uint32_t w){
  union { uint32_t u; float f; } cv; cv.u = w << 16; return cv.f;
}
__device__ __forceinline__ float bf16hi_to_f32(uint32_t w){
  union { uint32_t u; float f; } cv; cv.u = w & 0xFFFF0000u; return cv.f;
}

// DPP cross-lane add within a 16-lane row (xor1, xor2, ^7-in-8, mirror-16)
#define DPP_ADD(x, ctrl) ((x) + __int_as_float(__builtin_amdgcn_update_dpp(0, __float_as_int(x), (ctrl), 0xF, 0xF, true)))

// ---------------- prep kernels ----------------

__global__ __launch_bounds__(256) void k_prep_w1t(const float* __restrict__ W1,
                                                  unsigned short* __restrict__ W1T){
  int idx = blockIdx.x*256 + threadIdx.x;          // 128*1024, W1T[n][k]
  if(idx >= 128*1024) return;
  int n = idx >> 10, k = idx & 1023;
  W1T[idx] = f32_to_bf16(W1[k*128 + n]);
}

__global__ __launch_bounds__(256) void k_prep_w2t(const float* __restrict__ W2,
                                                  unsigned short* __restrict__ W2T){
  int idx = blockIdx.x*256 + threadIdx.x;          // 128*128, W2T[n][k]
  if(idx >= 128*128) return;
  int n = idx >> 7, k = idx & 127;
  W2T[idx] = f32_to_bf16(W2[k*128 + n]);
}

// Wg1T[c][k], c in [0,256): c<128 -> u-col uses Wg1[k][c]; c>=128 -> v-col uses Wg1[128+k][c-128]
__global__ __launch_bounds__(256) void k_prep_wg1T(const float* __restrict__ Wg1,
                                                   unsigned short* __restrict__ T){
  int idx = blockIdx.x*256 + threadIdx.x;          // 256*128
  if(idx >= 256*128) return;
  int c = idx >> 7, k = idx & 127;
  int row = (c < 128) ? k : (128 + k);
  int col = (c < 128) ? c : (c - 128);
  T[idx] = f32_to_bf16(Wg1[row*128 + col]);
}

// ---------------- CSR build: hist + 3-kernel parallel scan + fill ----------------

__global__ __launch_bounds__(256) void k_hist(const int* __restrict__ dst,
                                              int* __restrict__ counts){
  int e = blockIdx.x*256 + threadIdx.x;
  if(e < EE) atomicAdd(&counts[dst[e]], 1);
}

__global__ __launch_bounds__(256) void k_scan1(const int* __restrict__ counts,
    int* __restrict__ lexcl, int* __restrict__ bsum){
  __shared__ int buf[256];
  const int t = threadIdx.x, i = blockIdx.x*256 + t;
  int v = (i < NN) ? counts[i] : 0;
  buf[t] = v;
  __syncthreads();
  for(int off = 1; off < 256; off <<= 1){
    int add = (t >= off) ? buf[t-off] : 0;
    __syncthreads();
    buf[t] += add;
    __syncthreads();
  }
  if(i < NN) lexcl[i] = buf[t] - v;
  if(t == 255) bsum[blockIdx.x] = buf[255];
}

__global__ __launch_bounds__(256) void k_scan2(const int* __restrict__ bsum,
    int* __restrict__ bexcl, int* __restrict__ row_ptr){
  __shared__ int buf[256];
  const int t = threadIdx.x;
  int v = (t < SCAN_BLKS) ? bsum[t] : 0;
  buf[t] = v;
  __syncthreads();
  for(int off = 1; off < 256; off <<= 1){
    int add = (t >= off) ? buf[t-off] : 0;
    __syncthreads();
    buf[t] += add;
    __syncthreads();
  }
  if(t < SCAN_BLKS) bexcl[t] = buf[t] - v;
  if(t == 255) row_ptr[NN] = buf[255];
}

__global__ __launch_bounds__(256) void k_scan3(const int* __restrict__ lexcl,
    const int* __restrict__ bexcl, int* __restrict__ row_ptr, int* __restrict__ cursor){
  const int i = blockIdx.x*256 + threadIdx.x;
  if(i >= NN) return;
  int e = lexcl[i] + bexcl[blockIdx.x];
  row_ptr[i] = e;
  cursor[i]  = e;
}

// fill CSR slots; computes c = base_w*sig(rho_src)*sig(rho_dst) inline into permuted order
__global__ __launch_bounds__(256) void k_fill(const int* __restrict__ src,
    const int* __restrict__ dst, const float* __restrict__ base_w,
    const float* __restrict__ rho_raw, int* __restrict__ cursor,
    int* __restrict__ src_perm, float* __restrict__ c_perm){
  int e = blockIdx.x*256 + threadIdx.x;
  if(e >= EE) return;
  int s = src[e], d = dst[e];
  int p = atomicAdd(&cursor[d], 1);
  float rs = 1.f/(1.f + __expf(-rho_raw[s]));
  float rd = 1.f/(1.f + __expf(-rho_raw[d]));
  src_perm[p] = s;
  c_perm[p]   = base_w[e]*rs*rd;
}

// ---------------- encoder GEMM1: h1 = relu(X@W1 + b1) -> bf16 [N,128] ----------------
// Double-buffered LDS + depth-2 register prefetch, written as explicit even/odd
// 2-step bodies with NAMED register sets (no runtime-indexed reg arrays -> no scratch).
// setA holds even tiles, setB odd tiles. Load tile k+2 issued at step k,
// ds_written at end of step k+1, consumed at step k+2.

__global__ __launch_bounds__(256) void k_enc1(
    const float* __restrict__ X, const unsigned short* __restrict__ W1T,
    const float* __restrict__ b1, unsigned short* __restrict__ h1)
{
  __shared__ __attribute__((aligned(16))) unsigned short As[2][64*40];
  __shared__ __attribute__((aligned(16))) unsigned short Bs[2][128*40];

  const int t = threadIdx.x, w = t >> 6, lane = t & 63;
  const int rowL = lane & 15, kq = lane >> 4;
  const int wm = w >> 1, wn = w & 1;
  const int row0 = blockIdx.x * 64;

  const int arow = t >> 2, ac8  = (t & 3) * 8;
  const int brow = t >> 1, bk16 = (t & 1) * 16;
  int ag = row0 + arow; if(ag >= NN) ag = NN - 1;
  const float* xp = X + (size_t)ag*1024 + ac8;
  const unsigned short* wp = W1T + (size_t)brow*1024 + bk16;

  // named prefetch sets: A = even tiles, B = odd tiles
  f32x4 aA0, aA1, aB0, aB1; bf16x8 bA0, bA1, bB0, bB1;
  aA0 = *(const f32x4*)(xp);       aA1 = *(const f32x4*)(xp + 4);
  bA0 = *(const bf16x8*)(wp);      bA1 = *(const bf16x8*)(wp + 8);
  aB0 = *(const f32x4*)(xp + 32);  aB1 = *(const f32x4*)(xp + 36);
  bB0 = *(const bf16x8*)(wp + 32); bB1 = *(const bf16x8*)(wp + 40);

  { // stage tile 0 into LDS[0]
    union { bf16x8 v; unsigned short s[8]; } pk;
    #pragma unroll
    for(int j = 0; j < 4; j++){ pk.s[j] = f32_to_bf16(aA0[j]); pk.s[4+j] = f32_to_bf16(aA1[j]); }
    *(bf16x8*)&As[0][arow*40 + ac8] = pk.v;
    *(bf16x8*)&Bs[0][brow*40 + bk16]     = bA0;
    *(bf16x8*)&Bs[0][brow*40 + bk16 + 8] = bA1;
  }
  __syncthreads();

  f32x4 acc[2][4] = {};
  for(int kk = 0; kk < 16; kk++){
    // ---- even step k=2kk: compute LDS[0]; load tile 2kk+2 -> setA; stage setB (tile 2kk+1) -> LDS[1]
    {
      if(kk < 15){
        const int ko = kk*64 + 64;
        aA0 = *(const f32x4*)(xp + ko);  aA1 = *(const f32x4*)(xp + ko + 4);
        bA0 = *(const bf16x8*)(wp + ko); bA1 = *(const bf16x8*)(wp + ko + 8);
      }
      bf16x8 af[2], bfr[4];
      #pragma unroll
      for(int mf = 0; mf < 2; mf++)
        af[mf] = *(const bf16x8*)&As[0][(wm*32 + mf*16 + rowL)*40 + kq*8];
      #pragma unroll
      for(int nf = 0; nf < 4; nf++)
        bfr[nf] = *(const bf16x8*)&Bs[0][(wn*64 + nf*16 + rowL)*40 + kq*8];
      #pragma unroll
      for(int mf = 0; mf < 2; mf++)
        #pragma unroll
        for(int nf = 0; nf < 4; nf++)
          acc[mf][nf] = __builtin_amdgcn_mfma_f32_16x16x32_bf16(af[mf], bfr[nf], acc[mf][nf], 0, 0, 0);
      { // stage tile 2kk+1 (setB, loaded one step ago)
        union { bf16x8 v; unsigned short s[8]; } pk;
        #pragma unroll
        for(int j = 0; j < 4; j++){ pk.s[j] = f32_to_bf16(aB0[j]); pk.s[4+j] = f32_to_bf16(aB1[j]); }
        *(bf16x8*)&As[1][arow*40 + ac8] = pk.v;
        *(bf16x8*)&Bs[1][brow*40 + bk16]     = bB0;
        *(bf16x8*)&Bs[1][brow*40 + bk16 + 8] = bB1;
      }
      __syncthreads();
    }
    // ---- odd step k=2kk+1: compute LDS[1]; load tile 2kk+3 -> setB; stage setA (tile 2kk+2) -> LDS[0]
    {
      if(kk < 15){
        const int ko = kk*64 + 96;
        aB0 = *(const f32x4*)(xp + ko);  aB1 = *(const f32x4*)(xp + ko + 4);
        bB0 = *(const bf16x8*)(wp + ko); bB1 = *(const bf16x8*)(wp + ko + 8);
      }
      bf16x8 af[2], bfr[4];
      #pragma unroll
      for(int mf = 0; mf < 2; mf++)
        af[mf] = *(const bf16x8*)&As[1][(wm*32 + mf*16 + rowL)*40 + kq*8];
      #pragma unroll
      for(int nf = 0; nf < 4; nf++)
        bfr[nf] = *(const bf16x8*)&Bs[1][(wn*64 + nf*16 + rowL)*40 + kq*8];
      #pragma unroll
      for(int mf = 0; mf < 2; mf++)
        #pragma unroll
        for(int nf = 0; nf < 4; nf++)
          acc[mf][nf] = __builtin_amdgcn_mfma_f32_16x16x32_bf16(af[mf], bfr[nf], acc[mf][nf], 0, 0, 0);
      if(kk < 15){ // stage tile 2kk+2 (setA)
        union { bf16x8 v; unsigned short s[8]; } pk;
        #pragma unroll
        for(int j = 0; j < 4; j++){ pk.s[j] = f32_to_bf16(aA0[j]); pk.s[4+j] = f32_to_bf16(aA1[j]); }
        *(bf16x8*)&As[0][arow*40 + ac8] = pk.v;
        *(bf16x8*)&Bs[0][brow*40 + bk16]     = bA0;
        *(bf16x8*)&Bs[0][brow*40 + bk16 + 8] = bA1;
      }
      __syncthreads();
    }
  }

  // epilogue: bias + relu + bf16 store. C frag: row = kq*4+r, col = rowL.
  #pragma unroll
  for(int mf = 0; mf < 2; mf++){
    #pragma unroll
    for(int nf = 0; nf < 4; nf++){
      const int col = wn*64 + nf*16 + rowL;
      const float bv = b1[col];
      #pragma unroll
      for(int r = 0; r < 4; r++){
        const int gr = row0 + wm*32 + mf*16 + kq*4 + r;
        if(gr < NN) h1[(size_t)gr*128 + col] = f32_to_bf16(fmaxf(acc[mf][nf][r] + bv, 0.f));
      }
    }
  }
}

// ---------------- shared UV phase: [u|v] = h @ Wg1 from swizzled LDS (h AND Wg1T) ----------------
// hs: 64x128 bf16, chunk c of row r at chunk (c ^ (r&15)).
// wgl: 256x128 bf16, same swizzle keyed on (row&15).

__device__ __forceinline__ void uv_phase2(
    const unsigned short* hs, const unsigned short* wgl, int row0, int wave, int lane,
    const float* __restrict__ bg1,
    unsigned short* __restrict__ UH, float* __restrict__ Vf)
{
  const int rowL = lane & 15, kq = lane >> 4;
  const int r = wave*16 + rowL;                      // A row (local)
  f32x4 acc[16] = {};
  #pragma unroll
  for(int ks = 0; ks < 4; ks++){
    const int kc = ks*4 + kq;
    bf16x8 a = *(const bf16x8*)&hs[r*128 + ((kc ^ (r & 15)) << 3)];
    #pragma unroll
    for(int nt = 0; nt < 16; nt++){
      bf16x8 b = *(const bf16x8*)&wgl[(nt*16 + rowL)*128 + ((kc ^ rowL) << 3)];
      acc[nt] = __builtin_amdgcn_mfma_f32_16x16x32_bf16(a, b, acc[nt], 0, 0, 0);
    }
  }
  #pragma unroll
  for(int nt = 0; nt < 16; nt++){
    const int col = nt*16 + rowL;
    #pragma unroll
    for(int rr = 0; rr < 4; rr++){
      const int gr = row0 + wave*16 + kq*4 + rr;
      if(gr < NN){
        if(col < 128) UH[(size_t)gr*256 + col] = f32_to_bf16(acc[nt][rr]);
        else          Vf[(size_t)gr*128 + col - 128] = acc[nt][rr] + bg1[col - 128];
      }
    }
  }
}

// ---------------- k_uvA: h = relu(h1@W2T + b2); writes UH=[u|h] bf16, Vf=v+bg1 ----------------

__global__ __launch_bounds__(256) void k_uvA(
    const unsigned short* __restrict__ h1, const unsigned short* __restrict__ W2T,
    const float* __restrict__ b2, const unsigned short* __restrict__ Wg1T,
    const float* __restrict__ bg1, unsigned short* __restrict__ UH,
    float* __restrict__ Vf)
{
  __shared__ __attribute__((aligned(16))) unsigned short hs[64*128];
  __shared__ __attribute__((aligned(16))) unsigned short wgl[256*128];
  const int t = threadIdx.x, wave = t >> 6, lane = t & 63;
  const int rowL = lane & 15, kq = lane >> 4;
  const int row0 = blockIdx.x*64;

  // issue Wg1T loads early (latency hides under phase-1 MFMAs)
  bf16x8 wreg[16];
  #pragma unroll
  for(int i = 0; i < 16; i++)
    wreg[i] = *(const bf16x8*)(Wg1T + (i*256 + t)*8);

  // phase 1: h = relu(h1 @ W2T + b2); A direct from global h1, B from L2-resident W2T
  int ar = row0 + wave*16 + rowL; if(ar >= NN) ar = NN-1;
  f32x4 acc[8] = {};
  #pragma unroll
  for(int ks = 0; ks < 4; ks++){
    bf16x8 a = *(const bf16x8*)(h1 + (size_t)ar*128 + ks*32 + kq*8);
    #pragma unroll
    for(int nt = 0; nt < 8; nt++){
      bf16x8 b = *(const bf16x8*)(W2T + (nt*16 + rowL)*128 + ks*32 + kq*8);
      acc[nt] = __builtin_amdgcn_mfma_f32_16x16x32_bf16(a, b, acc[nt], 0, 0, 0);
    }
  }
  // h -> swizzled LDS (bf16 scalars)
  #pragma unroll
  for(int nt = 0; nt < 8; nt++){
    const int col = nt*16 + rowL;
    const float bv = b2[col];
    #pragma unroll
    for(int r = 0; r < 4; r++){
      const int rw = wave*16 + kq*4 + r;
      const unsigned short hv = f32_to_bf16(fmaxf(acc[nt][r] + bv, 0.f));
      hs[rw*128 + (((col >> 3) ^ (rw & 15)) << 3) + (col & 7)] = hv;
    }
  }
  // Wg1T -> swizzled LDS
  #pragma unroll
  for(int i = 0; i < 16; i++){
    const int idx = i*256 + t, row = idx >> 4, c = idx & 15;
    *(bf16x8*)&wgl[row*128 + ((c ^ (row & 15)) << 3)] = wreg[i];
  }
  __syncthreads();
  // copy h to UH h-half (coalesced 16B)
  {
    const int r = t >> 2, gr = row0 + r;
    if(gr < NN){
      #pragma unroll
      for(int j8 = 0; j8 < 4; j8++){
        const int chunk = (t & 3)*4 + j8;
        bf16x8 v = *(const bf16x8*)&hs[r*128 + ((chunk ^ (r & 15)) << 3)];
        *(bf16x8*)&UH[(size_t)gr*256 + 128 + chunk*8] = v;
      }
    }
  }
  uv_phase2(hs, wgl, row0, wave, lane, bg1, UH, Vf);
}

// ---------------- k_uvB: input h f32 (agg output); writes UH=[u|h] bf16, Vf=v+bg1 ----------------

__global__ __launch_bounds__(256) void k_uvB(
    const float* __restrict__ hf, const unsigned short* __restrict__ Wg1T,
    const float* __restrict__ bg1, unsigned short* __restrict__ UH,
    float* __restrict__ Vf)
{
  __shared__ __attribute__((aligned(16))) unsigned short hs[64*128];
  __shared__ __attribute__((aligned(16))) unsigned short wgl[256*128];
  const int t = threadIdx.x, wave = t >> 6, lane = t & 63;
  const int row0 = blockIdx.x*64;

  bf16x8 wreg[16];
  #pragma unroll
  for(int i = 0; i < 16; i++)
    wreg[i] = *(const bf16x8*)(Wg1T + (i*256 + t)*8);

  {
    const int r = t >> 2, gr0 = row0 + r;
    const int gr = (gr0 < NN) ? gr0 : NN-1;
    const float* p = hf + (size_t)gr*128 + (t & 3)*32;
    #pragma unroll
    for(int j8 = 0; j8 < 4; j8++){
      f32x4 v0 = *(const f32x4*)(p + j8*8);
      f32x4 v1 = *(const f32x4*)(p + j8*8 + 4);
      union { bf16x8 v; unsigned short s[8]; } pk;
      #pragma unroll
      for(int j = 0; j < 4; j++){ pk.s[j] = f32_to_bf16(v0[j]); pk.s[4+j] = f32_to_bf16(v1[j]); }
      const int chunk = (t & 3)*4 + j8;
      *(bf16x8*)&hs[r*128 + ((chunk ^ (r & 15)) << 3)] = pk.v;
      if(gr0 < NN) *(bf16x8*)&UH[(size_t)gr0*256 + 128 + chunk*8] = pk.v;
    }
  }
  #pragma unroll
  for(int i = 0; i < 16; i++){
    const int idx = i*256 + t, row = idx >> 4, c = idx & 15;
    *(bf16x8*)&wgl[row*128 + ((c ^ (row & 15)) << 3)] = wreg[i];
  }
  __syncthreads();
  uv_phase2(hs, wgl, row0, wave, lane & 63, bg1, UH, Vf);
}

// ---------------- fused gate + aggregation, CSR order, one wave per dst node ----------------
// gate: 4 edges/iter, 16 lanes/edge, DPP row reduction, 1-group software pipeline.

__global__ __launch_bounds__(256) void k_gate_agg(
    const unsigned short* __restrict__ UH, const float* __restrict__ Vf,
    const int* __restrict__ row_ptr, const int* __restrict__ src_perm,
    const float* __restrict__ c_perm,
    const float* __restrict__ Wg2, const float* __restrict__ bg2p,
    float* __restrict__ out_f32)
{
  __shared__ float2 ws_s[4][64];
  const int wv = threadIdx.x >> 6, lane = threadIdx.x & 63;
  const int gw = blockIdx.x*4 + wv;
  if(gw >= NN) return;
  const int eq = lane >> 4, li = lane & 15;

  f32x4 va = *(const f32x4*)(Vf + (size_t)gw*128 + li*8);
  f32x4 vb = *(const f32x4*)(Vf + (size_t)gw*128 + li*8 + 4);
  f32x4 wa = *(const f32x4*)(Wg2 + li*8);
  f32x4 wb = *(const f32x4*)(Wg2 + li*8 + 4);
  const float vch[8]  = {va[0],va[1],va[2],va[3],vb[0],vb[1],vb[2],vb[3]};
  const float w2ch[8] = {wa[0],wa[1],wa[2],wa[3],wb[0],wb[1],wb[2],wb[3]};
  const float bg2v = bg2p[0];

  const int beg = row_ptr[gw], end = row_ptr[gw+1];
  float a0 = 0.f, a1 = 0.f, wsum = 0.f;

  for(int base = beg; base < end; base += 64){
    const int nb = min(64, end - base);

    // ---- gate: software-pipelined, 4 edges/iter ----
    int s_c; float cv_c; bf16x8 u_c;
    {
      const int idx = eq, slot = base + ((idx < nb) ? idx : 0);
      s_c = src_perm[slot]; cv_c = c_perm[slot];
      u_c = *(const bf16x8*)&UH[(uint32_t)s_c*256u + li*8];
    }
    for(int q = 0; q < nb; q += 4){
      int s_n = 0; float cv_n = 0.f; bf16x8 u_n = {};
      if(q + 4 < nb){
        const int idx = q + 4 + eq, slot = base + ((idx < nb) ? idx : 0);
        s_n = src_perm[slot]; cv_n = c_perm[slot];
        u_n = *(const bf16x8*)&UH[(uint32_t)s_n*256u + li*8];
      }
      union { bf16x8 v; uint32_t u32[4]; } uu; uu.v = u_c;
      float tacc = 0.f;
      #pragma unroll
      for(int p = 0; p < 4; p++){
        const uint32_t w2b = uu.u32[p];
        tacc += fmaxf(bf16lo_to_f32(w2b) + vch[2*p],   0.f) * w2ch[2*p];
        tacc += fmaxf(bf16hi_to_f32(w2b) + vch[2*p+1], 0.f) * w2ch[2*p+1];
      }
      // DPP reduce over the 16-lane row: xor1, xor2, ^7-in-8, mirror-16
      tacc = DPP_ADD(tacc, 0xB1);
      tacc = DPP_ADD(tacc, 0x4E);
      tacc = DPP_ADD(tacc, 0x141);
      tacc = DPP_ADD(tacc, 0x140);
      const float g = 1.f/(1.f + __expf(-(tacc + bg2v)));
      const int idx = q + eq;
      if(li == 0 && idx < nb) ws_s[wv][idx] = make_float2(cv_c*g, __int_as_float(s_c));
      s_c = s_n; cv_c = cv_n; u_c = u_n;
    }

    // ---- aggregate (same-wave LDS producer/consumer; no barrier needed) ----
    #pragma unroll 8
    for(int j = 0; j < nb; j++){
      const float2 p = ws_s[wv][j];
      const float w  = p.x;
      const uint32_t s = (uint32_t)__float_as_int(p.y);
      const uint32_t hw = *(const uint32_t*)&UH[s*256u + 128u + lane*2];
      a0 += w*bf16lo_to_f32(hw);
      a1 += w*bf16hi_to_f32(hw);
      wsum += w;
    }
  }
  const float inv = 1.f/(wsum + EPSV);
  const size_t o = (size_t)gw*128 + lane*2;
  *(f32x2*)&out_f32[o] = (f32x2){a0*inv, a1*inv};
}

// ---------------- launch ----------------

extern "C" void kernel_launch(void* const* d_in, const int* in_sizes, int n_in,
                              void* d_out, int out_size, void* d_ws, size_t ws_size,
                              hipStream_t stream) {
  (void)in_sizes; (void)n_in; (void)out_size; (void)ws_size;
  const float* X      = (const float*)d_in[0];
  const int*   src    = (const int*)d_in[1];
  const int*   dst    = (const int*)d_in[2];
  const float* base_w = (const float*)d_in[3];
  const float* W1     = (const float*)d_in[4];
  const float* b1     = (const float*)d_in[5];
  const float* W2     = (const float*)d_in[6];
  const float* b2     = (const float*)d_in[7];
  const float* Wg1    = (const float*)d_in[8];
  const float* bg1    = (const float*)d_in[9];
  const float* Wg2    = (const float*)d_in[10];
  const float* bg2    = (const float*)d_in[11];
  const float* rho    = (const float*)d_in[12];

  char* ws = (char*)d_ws;
  size_t off = 0;
  auto alloc = [&](size_t bytes)->char*{ char* p = ws + off; off += (bytes + 255) & ~(size_t)255; return p; };
  unsigned short* W1T      = (unsigned short*)alloc((size_t)1024*128*2);
  unsigned short* W2T      = (unsigned short*)alloc((size_t)128*128*2);
  unsigned short* Wg1T     = (unsigned short*)alloc((size_t)256*128*2);
  int*            src_perm = (int*)alloc((size_t)EE*4);
  float*          c_perm   = (float*)alloc((size_t)EE*4);
  int*            row_ptr  = (int*)alloc((size_t)(NN+1)*4);
  int*            cursor   = (int*)alloc((size_t)NN*4);
  int*            counts   = (int*)alloc((size_t)NN*4);
  int*            lexcl    = (int*)alloc((size_t)NN*4);
  int*            bsum     = (int*)alloc((size_t)256*4);
  int*            bexcl    = (int*)alloc((size_t)256*4);
  unsigned short* h1       = (unsigned short*)alloc((size_t)NN*128*2);
  unsigned short* UH       = (unsigned short*)alloc((size_t)NN*256*2);
  float*          Vf       = (float*)alloc((size_t)NN*128*4);
  float*          hf_B     = (float*)alloc((size_t)NN*128*4);

  hipMemsetAsync(counts, 0, (size_t)NN*4, stream);
  k_prep_w1t<<<512, 256, 0, stream>>>(W1, W1T);
  k_prep_w2t<<<64, 256, 0, stream>>>(W2, W2T);
  k_prep_wg1T<<<128, 256, 0, stream>>>(Wg1, Wg1T);
  k_hist<<<EE/256, 256, 0, stream>>>(dst, counts);
  k_scan1<<<SCAN_BLKS, 256, 0, stream>>>(counts, lexcl, bsum);
  k_scan2<<<1, 256, 0, stream>>>(bsum, bexcl, row_ptr);
  k_scan3<<<SCAN_BLKS, 256, 0, stream>>>(lexcl, bexcl, row_ptr, cursor);
  k_fill<<<EE/256, 256, 0, stream>>>(src, dst, base_w, rho, cursor, src_perm, c_perm);

  k_enc1<<<782, 256, 0, stream>>>(X, W1T, b1, h1);

  // layer 1
  k_uvA<<<782, 256, 0, stream>>>(h1, W2T, b2, Wg1T, bg1, UH, Vf);
  k_gate_agg<<<12500, 256, 0, stream>>>(UH, Vf, row_ptr, src_perm, c_perm, Wg2, bg2, hf_B);
  // layer 2
  k_uvB<<<782, 256, 0, stream>>>(hf_B, Wg1T, bg1, UH, Vf);
  k_gate_agg<<<12500, 256, 0, stream>>>(UH, Vf, row_ptr, src_perm, c_perm, Wg2, bg2, (float*)d_out);
}

// Round 9
// 557.125 us; speedup vs baseline: 1.3826x; 1.0307x over previous
//
#include <hip/hip_runtime.h>
#include <stdint.h>

#define NN 50000
#define CC 1024
#define HH 128
#define EE 1600000
#define EPSV 1e-8f
#define SCAN_BLKS 196   // ceil(50000/256)

typedef __attribute__((ext_vector_type(8))) short bf16x8;
typedef __attribute__((ext_vector_type(4))) float f32x4;
typedef __attribute__((ext_vector_type(2))) float f32x2;

__device__ __forceinline__ unsigned short f32_to_bf16(float f){
  union { float f; uint32_t u; } cv; cv.f = f;
  uint32_t u = cv.u;
  return (unsigned short)((u + 0x7FFFu + ((u >> 16) & 1u)) >> 16);
}
__device__ __forceinline__ float bf16lo_to_f32(uint32_t w){
  union { uint32_t u; float f; } cv; cv.u = w << 16; return cv.f;
}
__device__ __forceinline__ float bf16hi_to_f32(uint32_t w){
  union { uint32_t u; float f; } cv; cv.u = w & 0xFFFF0000u; return cv.f;
}

// DPP cross-lane add within a 16-lane row (xor1, xor2, ^7-in-8, mirror-16)
#define DPP_ADD(x, ctrl) ((x) + __int_as_float(__builtin_amdgcn_update_dpp(0, __float_as_int(x), (ctrl), 0xF, 0xF, true)))

// async global->LDS 16B DMA (lds dst wave-uniform base + lane*16; global src per-lane)
#define GLOAD_LDS16(g, l) __builtin_amdgcn_global_load_lds( \
    (const __attribute__((address_space(1))) uint32_t*)(g), \
    (__attribute__((address_space(3))) uint32_t*)(l), 16, 0, 0)

// ---------------- merged weight prep: W1T, W2T, Wg1T ----------------

__global__ __launch_bounds__(256) void k_prep_all(
    const float* __restrict__ W1, const float* __restrict__ W2,
    const float* __restrict__ Wg1,
    unsigned short* __restrict__ W1T, unsigned short* __restrict__ W2T,
    unsigned short* __restrict__ Wg1T){
  int idx = blockIdx.x*256 + threadIdx.x;
  if(idx < 131072){                                   // W1T[n][k] = W1[k][n]
    int n = idx >> 10, k = idx & 1023;
    W1T[idx] = f32_to_bf16(W1[k*128 + n]);
  } else if(idx < 131072 + 16384){                    // W2T[n][k] = W2[k][n]
    int i = idx - 131072;
    int n = i >> 7, k = i & 127;
    W2T[i] = f32_to_bf16(W2[k*128 + n]);
  } else if(idx < 131072 + 16384 + 32768){            // Wg1T[c][k]
    int i = idx - 131072 - 16384;
    int c = i >> 7, k = i & 127;
    int row = (c < 128) ? k : (128 + k);
    int col = (c < 128) ? c : (c - 128);
    Wg1T[i] = f32_to_bf16(Wg1[row*128 + col]);
  }
}

// ---------------- CSR build: hist + 3-kernel parallel scan + fill ----------------

__global__ __launch_bounds__(256) void k_hist(const int* __restrict__ dst,
                                              int* __restrict__ counts){
  int e = blockIdx.x*256 + threadIdx.x;
  if(e < EE) atomicAdd(&counts[dst[e]], 1);
}

__global__ __launch_bounds__(256) void k_scan1(const int* __restrict__ counts,
    int* __restrict__ lexcl, int* __restrict__ bsum){
  __shared__ int buf[256];
  const int t = threadIdx.x, i = blockIdx.x*256 + t;
  int v = (i < NN) ? counts[i] : 0;
  buf[t] = v;
  __syncthreads();
  for(int off = 1; off < 256; off <<= 1){
    int add = (t >= off) ? buf[t-off] : 0;
    __syncthreads();
    buf[t] += add;
    __syncthreads();
  }
  if(i < NN) lexcl[i] = buf[t] - v;
  if(t == 255) bsum[blockIdx.x] = buf[255];
}

__global__ __launch_bounds__(256) void k_scan2(const int* __restrict__ bsum,
    int* __restrict__ bexcl, int* __restrict__ row_ptr){
  __shared__ int buf[256];
  const int t = threadIdx.x;
  int v = (t < SCAN_BLKS) ? bsum[t] : 0;
  buf[t] = v;
  __syncthreads();
  for(int off = 1; off < 256; off <<= 1){
    int add = (t >= off) ? buf[t-off] : 0;
    __syncthreads();
    buf[t] += add;
    __syncthreads();
  }
  if(t < SCAN_BLKS) bexcl[t] = buf[t] - v;
  if(t == 255) row_ptr[NN] = buf[255];
}

__global__ __launch_bounds__(256) void k_scan3(const int* __restrict__ lexcl,
    const int* __restrict__ bexcl, int* __restrict__ row_ptr, int* __restrict__ cursor){
  const int i = blockIdx.x*256 + threadIdx.x;
  if(i >= NN) return;
  int e = lexcl[i] + bexcl[blockIdx.x];
  row_ptr[i] = e;
  cursor[i]  = e;
}

// fill CSR slots; computes c = base_w*sig(rho_src)*sig(rho_dst) inline into permuted order
__global__ __launch_bounds__(256) void k_fill(const int* __restrict__ src,
    const int* __restrict__ dst, const float* __restrict__ base_w,
    const float* __restrict__ rho_raw, int* __restrict__ cursor,
    int* __restrict__ src_perm, float* __restrict__ c_perm){
  int e = blockIdx.x*256 + threadIdx.x;
  if(e >= EE) return;
  int s = src[e], d = dst[e];
  int p = atomicAdd(&cursor[d], 1);
  float rs = 1.f/(1.f + __expf(-rho_raw[s]));
  float rd = 1.f/(1.f + __expf(-rho_raw[d]));
  src_perm[p] = s;
  c_perm[p]   = base_w[e]*rs*rd;
}

// ---------------- encoder GEMM1: h1 = relu(X@W1 + b1) -> bf16 [N,128] ----------------
// m97-style: ALL staging via global_load_lds (async DMA, no VGPR round-trip).
// A staged as f32 (converted at fragment read), B bf16. LDS linear, conflict
// avoided by pre-swizzling the GLOBAL source chunk index (T21 both-sides rule):
//   A [64 rows][8 chunks of 16B]: chunk_lds c holds global chunk c ^ (row&7)
//   B [128 rows][4 chunks of 16B]: chunk_lds c holds global chunk c ^ key(row),
//     key(r) = (r ^ (r>>2)) & 3  (depends only on r mod 16)
// Double-buffered; DMA for tile k+1 issued at top of step k; one barrier/step.

__global__ __launch_bounds__(256) void k_enc1(
    const float* __restrict__ X, const unsigned short* __restrict__ W1T,
    const float* __restrict__ b1, unsigned short* __restrict__ h1)
{
  __shared__ __attribute__((aligned(16))) float          Af[2][64*32];    // 8KB each
  __shared__ __attribute__((aligned(16))) unsigned short Bf[2][128*32];   // 8KB each

  const int t = threadIdx.x, w = t >> 6, lane = t & 63;
  const int rowL = lane & 15, kq = lane >> 4;
  const int wm = w >> 1, wn = w & 1;
  const int row0 = blockIdx.x * 64;

  // ---- per-lane DMA source setup ----
  // A: wave w covers rows 16w..16w+15, two 1KB calls (8 rows each).
  const int a_rl0 = w*16 + (lane >> 3);            // call q adds 8q
  const int a_cl  = lane & 7;
  int agr0 = row0 + a_rl0;     if(agr0 >= NN) agr0 = NN-1;
  int agr1 = row0 + a_rl0 + 8; if(agr1 >= NN) agr1 = NN-1;
  const float* a_src0 = X + (size_t)agr0*1024 + (a_cl ^ (a_rl0 & 7))*4;
  const float* a_src1 = X + (size_t)agr1*1024 + (a_cl ^ ((a_rl0+8) & 7))*4;
  // B: wave w covers rows 32w..32w+31, two 1KB calls (16 rows each).
  const int b_rl0 = w*32 + (lane >> 2);            // call q adds 16q
  const int b_cl  = lane & 3;
  const int bkey0 = (b_rl0 ^ (b_rl0 >> 2)) & 3;
  const int bkey1 = ((b_rl0+16) ^ ((b_rl0+16) >> 2)) & 3;
  const unsigned short* b_src0 = W1T + (size_t)b_rl0*1024 + (b_cl ^ bkey0)*8;
  const unsigned short* b_src1 = W1T + (size_t)(b_rl0+16)*1024 + (b_cl ^ bkey1)*8;

  #define STAGE(buf, k0)  do{                                              \
    GLOAD_LDS16(a_src0 + (k0), &Af[buf][(w*16    )*32]);                   \
    GLOAD_LDS16(a_src1 + (k0), &Af[buf][(w*16 + 8)*32]);                   \
    GLOAD_LDS16(b_src0 + (k0), &Bf[buf][(w*32     )*32]);                  \
    GLOAD_LDS16(b_src1 + (k0), &Bf[buf][(w*32 + 16)*32]);                  \
  }while(0)

  STAGE(0, 0);
  __syncthreads();

  f32x4 acc[2][4] = {};
  const int arow0 = wm*32 + rowL;                  // + mf*16
  const int akey  = rowL & 7;
  const int bkeyR = (rowL ^ (rowL >> 2)) & 3;

  int cur = 0;
  for(int step = 0; step < 32; step++){
    if(step < 31) STAGE(cur^1, (step+1)*32);
    // A fragments: two 16B chunks per mf, f32 -> bf16 at read
    bf16x8 af[2];
    #pragma unroll
    for(int mf = 0; mf < 2; mf++){
      const int ar = arow0 + mf*16;
      f32x4 x0 = *(const f32x4*)&Af[cur][ar*32 + (((2*kq  ) ^ akey) << 2)];
      f32x4 x1 = *(const f32x4*)&Af[cur][ar*32 + (((2*kq+1) ^ akey) << 2)];
      union { bf16x8 v; unsigned short s[8]; } pk;
      #pragma unroll
      for(int j = 0; j < 4; j++){ pk.s[j] = f32_to_bf16(x0[j]); pk.s[4+j] = f32_to_bf16(x1[j]); }
      af[mf] = pk.v;
    }
    bf16x8 bfr[4];
    #pragma unroll
    for(int nf = 0; nf < 4; nf++){
      const int br = wn*64 + nf*16 + rowL;
      bfr[nf] = *(const bf16x8*)&Bf[cur][br*32 + ((kq ^ bkeyR) << 3)];
    }
    #pragma unroll
    for(int mf = 0; mf < 2; mf++)
      #pragma unroll
      for(int nf = 0; nf < 4; nf++)
        acc[mf][nf] = __builtin_amdgcn_mfma_f32_16x16x32_bf16(af[mf], bfr[nf], acc[mf][nf], 0, 0, 0);
    __syncthreads();
    cur ^= 1;
  }
  #undef STAGE

  // epilogue: bias + relu + bf16 store. C frag: row = kq*4+r, col = rowL.
  #pragma unroll
  for(int mf = 0; mf < 2; mf++){
    #pragma unroll
    for(int nf = 0; nf < 4; nf++){
      const int col = wn*64 + nf*16 + rowL;
      const float bv = b1[col];
      #pragma unroll
      for(int r = 0; r < 4; r++){
        const int gr = row0 + wm*32 + mf*16 + kq*4 + r;
        if(gr < NN) h1[(size_t)gr*128 + col] = f32_to_bf16(fmaxf(acc[mf][nf][r] + bv, 0.f));
      }
    }
  }
}

// ---------------- shared UV phase: [u|v] = h @ Wg1 from swizzled LDS (h AND Wg1T) ----------------
// hs: 64x128 bf16, chunk c of row r at chunk (c ^ (r&15)).
// wgl: 256x128 bf16, same swizzle keyed on (row&15).

__device__ __forceinline__ void uv_phase2(
    const unsigned short* hs, const unsigned short* wgl, int row0, int wave, int lane,
    const float* __restrict__ bg1,
    unsigned short* __restrict__ UH, float* __restrict__ Vf)
{
  const int rowL = lane & 15, kq = lane >> 4;
  const int r = wave*16 + rowL;                      // A row (local)
  f32x4 acc[16] = {};
  #pragma unroll
  for(int ks = 0; ks < 4; ks++){
    const int kc = ks*4 + kq;
    bf16x8 a = *(const bf16x8*)&hs[r*128 + ((kc ^ (r & 15)) << 3)];
    #pragma unroll
    for(int nt = 0; nt < 16; nt++){
      bf16x8 b = *(const bf16x8*)&wgl[(nt*16 + rowL)*128 + ((kc ^ rowL) << 3)];
      acc[nt] = __builtin_amdgcn_mfma_f32_16x16x32_bf16(a, b, acc[nt], 0, 0, 0);
    }
  }
  #pragma unroll
  for(int nt = 0; nt < 16; nt++){
    const int col = nt*16 + rowL;
    #pragma unroll
    for(int rr = 0; rr < 4; rr++){
      const int gr = row0 + wave*16 + kq*4 + rr;
      if(gr < NN){
        if(col < 128) UH[(size_t)gr*256 + col] = f32_to_bf16(acc[nt][rr]);
        else          Vf[(size_t)gr*128 + col - 128] = acc[nt][rr] + bg1[col - 128];
      }
    }
  }
}

// ---------------- k_uvA: h = relu(h1@W2T + b2); writes UH=[u|h] bf16, Vf=v+bg1 ----------------

__global__ __launch_bounds__(256) void k_uvA(
    const unsigned short* __restrict__ h1, const unsigned short* __restrict__ W2T,
    const float* __restrict__ b2, const unsigned short* __restrict__ Wg1T,
    const float* __restrict__ bg1, unsigned short* __restrict__ UH,
    float* __restrict__ Vf)
{
  __shared__ __attribute__((aligned(16))) unsigned short hs[64*128];
  __shared__ __attribute__((aligned(16))) unsigned short wgl[256*128];
  const int t = threadIdx.x, wave = t >> 6, lane = t & 63;
  const int rowL = lane & 15, kq = lane >> 4;
  const int row0 = blockIdx.x*64;

  // issue Wg1T loads early (latency hides under phase-1 MFMAs)
  bf16x8 wreg[16];
  #pragma unroll
  for(int i = 0; i < 16; i++)
    wreg[i] = *(const bf16x8*)(Wg1T + (i*256 + t)*8);

  // phase 1: h = relu(h1 @ W2T + b2); A direct from global h1, B from L2-resident W2T
  int ar = row0 + wave*16 + rowL; if(ar >= NN) ar = NN-1;
  f32x4 acc[8] = {};
  #pragma unroll
  for(int ks = 0; ks < 4; ks++){
    bf16x8 a = *(const bf16x8*)(h1 + (size_t)ar*128 + ks*32 + kq*8);
    #pragma unroll
    for(int nt = 0; nt < 8; nt++){
      bf16x8 b = *(const bf16x8*)(W2T + (nt*16 + rowL)*128 + ks*32 + kq*8);
      acc[nt] = __builtin_amdgcn_mfma_f32_16x16x32_bf16(a, b, acc[nt], 0, 0, 0);
    }
  }
  // h -> swizzled LDS (bf16 scalars)
  #pragma unroll
  for(int nt = 0; nt < 8; nt++){
    const int col = nt*16 + rowL;
    const float bv = b2[col];
    #pragma unroll
    for(int r = 0; r < 4; r++){
      const int rw = wave*16 + kq*4 + r;
      const unsigned short hv = f32_to_bf16(fmaxf(acc[nt][r] + bv, 0.f));
      hs[rw*128 + (((col >> 3) ^ (rw & 15)) << 3) + (col & 7)] = hv;
    }
  }
  // Wg1T -> swizzled LDS
  #pragma unroll
  for(int i = 0; i < 16; i++){
    const int idx = i*256 + t, row = idx >> 4, c = idx & 15;
    *(bf16x8*)&wgl[row*128 + ((c ^ (row & 15)) << 3)] = wreg[i];
  }
  __syncthreads();
  // copy h to UH h-half (coalesced 16B)
  {
    const int r = t >> 2, gr = row0 + r;
    if(gr < NN){
      #pragma unroll
      for(int j8 = 0; j8 < 4; j8++){
        const int chunk = (t & 3)*4 + j8;
        bf16x8 v = *(const bf16x8*)&hs[r*128 + ((chunk ^ (r & 15)) << 3)];
        *(bf16x8*)&UH[(size_t)gr*256 + 128 + chunk*8] = v;
      }
    }
  }
  uv_phase2(hs, wgl, row0, wave, lane, bg1, UH, Vf);
}

// ---------------- k_uvB: input h f32 (agg output); writes UH=[u|h] bf16, Vf=v+bg1 ----------------

__global__ __launch_bounds__(256) void k_uvB(
    const float* __restrict__ hf, const unsigned short* __restrict__ Wg1T,
    const float* __restrict__ bg1, unsigned short* __restrict__ UH,
    float* __restrict__ Vf)
{
  __shared__ __attribute__((aligned(16))) unsigned short hs[64*128];
  __shared__ __attribute__((aligned(16))) unsigned short wgl[256*128];
  const int t = threadIdx.x, wave = t >> 6, lane = t & 63;
  const int row0 = blockIdx.x*64;

  bf16x8 wreg[16];
  #pragma unroll
  for(int i = 0; i < 16; i++)
    wreg[i] = *(const bf16x8*)(Wg1T + (i*256 + t)*8);

  {
    const int r = t >> 2, gr0 = row0 + r;
    const int gr = (gr0 < NN) ? gr0 : NN-1;
    const float* p = hf + (size_t)gr*128 + (t & 3)*32;
    #pragma unroll
    for(int j8 = 0; j8 < 4; j8++){
      f32x4 v0 = *(const f32x4*)(p + j8*8);
      f32x4 v1 = *(const f32x4*)(p + j8*8 + 4);
      union { bf16x8 v; unsigned short s[8]; } pk;
      #pragma unroll
      for(int j = 0; j < 4; j++){ pk.s[j] = f32_to_bf16(v0[j]); pk.s[4+j] = f32_to_bf16(v1[j]); }
      const int chunk = (t & 3)*4 + j8;
      *(bf16x8*)&hs[r*128 + ((chunk ^ (r & 15)) << 3)] = pk.v;
      if(gr0 < NN) *(bf16x8*)&UH[(size_t)gr0*256 + 128 + chunk*8] = pk.v;
    }
  }
  #pragma unroll
  for(int i = 0; i < 16; i++){
    const int idx = i*256 + t, row = idx >> 4, c = idx & 15;
    *(bf16x8*)&wgl[row*128 + ((c ^ (row & 15)) << 3)] = wreg[i];
  }
  __syncthreads();
  uv_phase2(hs, wgl, row0, wave, lane & 63, bg1, UH, Vf);
}

// ---------------- fused gate + aggregation, CSR order, one wave per dst node ----------------
// gate: 4 edges/iter, 16 lanes/edge, DPP row reduction, 1-group software pipeline.

__global__ __launch_bounds__(256) void k_gate_agg(
    const unsigned short* __restrict__ UH, const float* __restrict__ Vf,
    const int* __restrict__ row_ptr, const int* __restrict__ src_perm,
    const float* __restrict__ c_perm,
    const float* __restrict__ Wg2, const float* __restrict__ bg2p,
    float* __restrict__ out_f32)
{
  __shared__ float2 ws_s[4][64];
  const int wv = threadIdx.x >> 6, lane = threadIdx.x & 63;
  const int gw = blockIdx.x*4 + wv;
  if(gw >= NN) return;
  const int eq = lane >> 4, li = lane & 15;

  f32x4 va = *(const f32x4*)(Vf + (size_t)gw*128 + li*8);
  f32x4 vb = *(const f32x4*)(Vf + (size_t)gw*128 + li*8 + 4);
  f32x4 wa = *(const f32x4*)(Wg2 + li*8);
  f32x4 wb = *(const f32x4*)(Wg2 + li*8 + 4);
  const float vch[8]  = {va[0],va[1],va[2],va[3],vb[0],vb[1],vb[2],vb[3]};
  const float w2ch[8] = {wa[0],wa[1],wa[2],wa[3],wb[0],wb[1],wb[2],wb[3]};
  const float bg2v = bg2p[0];

  const int beg = row_ptr[gw], end = row_ptr[gw+1];
  float a0 = 0.f, a1 = 0.f, wsum = 0.f;

  for(int base = beg; base < end; base += 64){
    const int nb = min(64, end - base);

    // ---- gate: software-pipelined, 4 edges/iter ----
    int s_c; float cv_c; bf16x8 u_c;
    {
      const int idx = eq, slot = base + ((idx < nb) ? idx : 0);
      s_c = src_perm[slot]; cv_c = c_perm[slot];
      u_c = *(const bf16x8*)&UH[(uint32_t)s_c*256u + li*8];
    }
    for(int q = 0; q < nb; q += 4){
      int s_n = 0; float cv_n = 0.f; bf16x8 u_n = {};
      if(q + 4 < nb){
        const int idx = q + 4 + eq, slot = base + ((idx < nb) ? idx : 0);
        s_n = src_perm[slot]; cv_n = c_perm[slot];
        u_n = *(const bf16x8*)&UH[(uint32_t)s_n*256u + li*8];
      }
      union { bf16x8 v; uint32_t u32[4]; } uu; uu.v = u_c;
      float tacc = 0.f;
      #pragma unroll
      for(int p = 0; p < 4; p++){
        const uint32_t w2b = uu.u32[p];
        tacc += fmaxf(bf16lo_to_f32(w2b) + vch[2*p],   0.f) * w2ch[2*p];
        tacc += fmaxf(bf16hi_to_f32(w2b) + vch[2*p+1], 0.f) * w2ch[2*p+1];
      }
      // DPP reduce over the 16-lane row: xor1, xor2, ^7-in-8, mirror-16
      tacc = DPP_ADD(tacc, 0xB1);
      tacc = DPP_ADD(tacc, 0x4E);
      tacc = DPP_ADD(tacc, 0x141);
      tacc = DPP_ADD(tacc, 0x140);
      const float g = 1.f/(1.f + __expf(-(tacc + bg2v)));
      const int idx = q + eq;
      if(li == 0 && idx < nb) ws_s[wv][idx] = make_float2(cv_c*g, __int_as_float(s_c));
      s_c = s_n; cv_c = cv_n; u_c = u_n;
    }

    // ---- aggregate (same-wave LDS producer/consumer; no barrier needed) ----
    #pragma unroll 8
    for(int j = 0; j < nb; j++){
      const float2 p = ws_s[wv][j];
      const float w  = p.x;
      const uint32_t s = (uint32_t)__float_as_int(p.y);
      const uint32_t hw = *(const uint32_t*)&UH[s*256u + 128u + lane*2];
      a0 += w*bf16lo_to_f32(hw);
      a1 += w*bf16hi_to_f32(hw);
      wsum += w;
    }
  }
  const float inv = 1.f/(wsum + EPSV);
  const size_t o = (size_t)gw*128 + lane*2;
  *(f32x2*)&out_f32[o] = (f32x2){a0*inv, a1*inv};
}

// ---------------- launch ----------------

extern "C" void kernel_launch(void* const* d_in, const int* in_sizes, int n_in,
                              void* d_out, int out_size, void* d_ws, size_t ws_size,
                              hipStream_t stream) {
  (void)in_sizes; (void)n_in; (void)out_size; (void)ws_size;
  const float* X      = (const float*)d_in[0];
  const int*   src    = (const int*)d_in[1];
  const int*   dst    = (const int*)d_in[2];
  const float* base_w = (const float*)d_in[3];
  const float* W1     = (const float*)d_in[4];
  const float* b1     = (const float*)d_in[5];
  const float* W2     = (const float*)d_in[6];
  const float* b2     = (const float*)d_in[7];
  const float* Wg1    = (const float*)d_in[8];
  const float* bg1    = (const float*)d_in[9];
  const float* Wg2    = (const float*)d_in[10];
  const float* bg2    = (const float*)d_in[11];
  const float* rho    = (const float*)d_in[12];

  char* ws = (char*)d_ws;
  size_t off = 0;
  auto alloc = [&](size_t bytes)->char*{ char* p = ws + off; off += (bytes + 255) & ~(size_t)255; return p; };
  unsigned short* W1T      = (unsigned short*)alloc((size_t)1024*128*2);
  unsigned short* W2T      = (unsigned short*)alloc((size_t)128*128*2);
  unsigned short* Wg1T     = (unsigned short*)alloc((size_t)256*128*2);
  int*            src_perm = (int*)alloc((size_t)EE*4);
  float*          c_perm   = (float*)alloc((size_t)EE*4);
  int*            row_ptr  = (int*)alloc((size_t)(NN+1)*4);
  int*            cursor   = (int*)alloc((size_t)NN*4);
  int*            counts   = (int*)alloc((size_t)NN*4);
  int*            lexcl    = (int*)alloc((size_t)NN*4);
  int*            bsum     = (int*)alloc((size_t)256*4);
  int*            bexcl    = (int*)alloc((size_t)256*4);
  unsigned short* h1       = (unsigned short*)alloc((size_t)NN*128*2);
  unsigned short* UH       = (unsigned short*)alloc((size_t)NN*256*2);
  float*          Vf       = (float*)alloc((size_t)NN*128*4);
  float*          hf_B     = (float*)alloc((size_t)NN*128*4);

  hipMemsetAsync(counts, 0, (size_t)NN*4, stream);
  k_prep_all<<<704, 256, 0, stream>>>(W1, W2, Wg1, W1T, W2T, Wg1T);
  k_hist<<<EE/256, 256, 0, stream>>>(dst, counts);
  k_scan1<<<SCAN_BLKS, 256, 0, stream>>>(counts, lexcl, bsum);
  k_scan2<<<1, 256, 0, stream>>>(bsum, bexcl, row_ptr);
  k_scan3<<<SCAN_BLKS, 256, 0, stream>>>(lexcl, bexcl, row_ptr, cursor);
  k_fill<<<EE/256, 256, 0, stream>>>(src, dst, base_w, rho, cursor, src_perm, c_perm);

  k_enc1<<<782, 256, 0, stream>>>(X, W1T, b1, h1);

  // layer 1
  k_uvA<<<782, 256, 0, stream>>>(h1, W2T, b2, Wg1T, bg1, UH, Vf);
  k_gate_agg<<<12500, 256, 0, stream>>>(UH, Vf, row_ptr, src_perm, c_perm, Wg2, bg2, hf_B);
  // layer 2
  k_uvB<<<782, 256, 0, stream>>>(hf_B, Wg1T, bg1, UH, Vf);
  k_gate_agg<<<12500, 256, 0, stream>>>(UH, Vf, row_ptr, src_perm, c_perm, Wg2, bg2, (float*)d_out);
}

// Round 10
// 490.930 us; speedup vs baseline: 1.5690x; 1.1348x over previous
//
#include <hip/hip_runtime.h>
#include <stdint.h>

#define NN 50000
#define CC 1024
#define HH 128
#define EE 1600000
#define EPSV 1e-8f
#define SCAN_BLKS 196   // ceil(50000/256)

typedef __attribute__((ext_vector_type(8))) short bf16x8;
typedef __attribute__((ext_vector_type(4))) float f32x4;
typedef __attribute__((ext_vector_type(2))) float f32x2;

__device__ __forceinline__ unsigned short f32_to_bf16(float f){
  union { float f; uint32_t u; } cv; cv.f = f;
  uint32_t u = cv.u;
  return (unsigned short)((u + 0x7FFFu + ((u >> 16) & 1u)) >> 16);
}
__device__ __forceinline__ float bf16lo_to_f32(uint32_t w){
  union { uint32_t u; float f; } cv; cv.u = w << 16; return cv.f;
}
__device__ __forceinline__ float bf16hi_to_f32(uint32_t w){
  union { uint32_t u; float f; } cv; cv.u = w & 0xFFFF0000u; return cv.f;
}

// DPP cross-lane add within a 16-lane row (xor1, xor2, ^7-in-8, mirror-16)
#define DPP_ADD(x, ctrl) ((x) + __int_as_float(__builtin_amdgcn_update_dpp(0, __float_as_int(x), (ctrl), 0xF, 0xF, true)))

// async global->LDS 16B DMA (lds dst wave-uniform base + lane*16; global src per-lane)
#define GLOAD_LDS16(g, l) __builtin_amdgcn_global_load_lds( \
    (const __attribute__((address_space(1))) uint32_t*)(g), \
    (__attribute__((address_space(3))) uint32_t*)(l), 16, 0, 0)

// ---------------- merged weight prep: W1T, W2T, Wg1T ----------------

__global__ __launch_bounds__(256) void k_prep_all(
    const float* __restrict__ W1, const float* __restrict__ W2,
    const float* __restrict__ Wg1,
    unsigned short* __restrict__ W1T, unsigned short* __restrict__ W2T,
    unsigned short* __restrict__ Wg1T){
  int idx = blockIdx.x*256 + threadIdx.x;
  if(idx < 131072){                                   // W1T[n][k] = W1[k][n]
    int n = idx >> 10, k = idx & 1023;
    W1T[idx] = f32_to_bf16(W1[k*128 + n]);
  } else if(idx < 131072 + 16384){                    // W2T[n][k] = W2[k][n]
    int i = idx - 131072;
    int n = i >> 7, k = i & 127;
    W2T[i] = f32_to_bf16(W2[k*128 + n]);
  } else if(idx < 131072 + 16384 + 32768){            // Wg1T[c][k]
    int i = idx - 131072 - 16384;
    int c = i >> 7, k = i & 127;
    int row = (c < 128) ? k : (128 + k);
    int col = (c < 128) ? c : (c - 128);
    Wg1T[i] = f32_to_bf16(Wg1[row*128 + col]);
  }
}

// ---------------- CSR build: hist(+rank) + parallel scan + atomic-free fill ----------------

__global__ __launch_bounds__(256) void k_hist(const int* __restrict__ dst,
                                              int* __restrict__ counts,
                                              int* __restrict__ rank){
  int e = blockIdx.x*256 + threadIdx.x;
  if(e < EE) rank[e] = atomicAdd(&counts[dst[e]], 1);
}

__global__ __launch_bounds__(256) void k_scan1(const int* __restrict__ counts,
    int* __restrict__ lexcl, int* __restrict__ bsum){
  __shared__ int buf[256];
  const int t = threadIdx.x, i = blockIdx.x*256 + t;
  int v = (i < NN) ? counts[i] : 0;
  buf[t] = v;
  __syncthreads();
  for(int off = 1; off < 256; off <<= 1){
    int add = (t >= off) ? buf[t-off] : 0;
    __syncthreads();
    buf[t] += add;
    __syncthreads();
  }
  if(i < NN) lexcl[i] = buf[t] - v;
  if(t == 255) bsum[blockIdx.x] = buf[255];
}

__global__ __launch_bounds__(256) void k_scan2(const int* __restrict__ bsum,
    int* __restrict__ bexcl, int* __restrict__ row_ptr){
  __shared__ int buf[256];
  const int t = threadIdx.x;
  int v = (t < SCAN_BLKS) ? bsum[t] : 0;
  buf[t] = v;
  __syncthreads();
  for(int off = 1; off < 256; off <<= 1){
    int add = (t >= off) ? buf[t-off] : 0;
    __syncthreads();
    buf[t] += add;
    __syncthreads();
  }
  if(t < SCAN_BLKS) bexcl[t] = buf[t] - v;
  if(t == 255) row_ptr[NN] = buf[255];
}

__global__ __launch_bounds__(256) void k_scan3(const int* __restrict__ lexcl,
    const int* __restrict__ bexcl, int* __restrict__ row_ptr){
  const int i = blockIdx.x*256 + threadIdx.x;
  if(i >= NN) return;
  row_ptr[i] = lexcl[i] + bexcl[blockIdx.x];
}

// atomic-free fill: p = row_ptr[dst] + rank; writes packed {c, src_bits}
__global__ __launch_bounds__(256) void k_fill(const int* __restrict__ src,
    const int* __restrict__ dst, const float* __restrict__ base_w,
    const float* __restrict__ rho_raw, const int* __restrict__ row_ptr,
    const int* __restrict__ rank, float2* __restrict__ scp){
  int e = blockIdx.x*256 + threadIdx.x;
  if(e >= EE) return;
  int s = src[e], d = dst[e];
  int p = row_ptr[d] + rank[e];
  float rs = 1.f/(1.f + __expf(-rho_raw[s]));
  float rd = 1.f/(1.f + __expf(-rho_raw[d]));
  scp[p] = make_float2(base_w[e]*rs*rd, __int_as_float(s));
}

// ---------------- encoder GEMM1: h1 = relu(X@W1 + b1) -> bf16 [N,128] ----------------
// m97-style: ALL staging via global_load_lds (async DMA, no VGPR round-trip).
// A staged as f32 (converted at fragment read), B bf16. LDS linear, conflict
// avoided by pre-swizzling the GLOBAL source chunk index (T21 both-sides rule).

__global__ __launch_bounds__(256) void k_enc1(
    const float* __restrict__ X, const unsigned short* __restrict__ W1T,
    const float* __restrict__ b1, unsigned short* __restrict__ h1)
{
  __shared__ __attribute__((aligned(16))) float          Af[2][64*32];    // 8KB each
  __shared__ __attribute__((aligned(16))) unsigned short Bf[2][128*32];   // 8KB each

  const int t = threadIdx.x, w = t >> 6, lane = t & 63;
  const int rowL = lane & 15, kq = lane >> 4;
  const int wm = w >> 1, wn = w & 1;
  const int row0 = blockIdx.x * 64;

  const int a_rl0 = w*16 + (lane >> 3);
  const int a_cl  = lane & 7;
  int agr0 = row0 + a_rl0;     if(agr0 >= NN) agr0 = NN-1;
  int agr1 = row0 + a_rl0 + 8; if(agr1 >= NN) agr1 = NN-1;
  const float* a_src0 = X + (size_t)agr0*1024 + (a_cl ^ (a_rl0 & 7))*4;
  const float* a_src1 = X + (size_t)agr1*1024 + (a_cl ^ ((a_rl0+8) & 7))*4;
  const int b_rl0 = w*32 + (lane >> 2);
  const int b_cl  = lane & 3;
  const int bkey0 = (b_rl0 ^ (b_rl0 >> 2)) & 3;
  const int bkey1 = ((b_rl0+16) ^ ((b_rl0+16) >> 2)) & 3;
  const unsigned short* b_src0 = W1T + (size_t)b_rl0*1024 + (b_cl ^ bkey0)*8;
  const unsigned short* b_src1 = W1T + (size_t)(b_rl0+16)*1024 + (b_cl ^ bkey1)*8;

  #define STAGE(buf, k0)  do{                                              \
    GLOAD_LDS16(a_src0 + (k0), &Af[buf][(w*16    )*32]);                   \
    GLOAD_LDS16(a_src1 + (k0), &Af[buf][(w*16 + 8)*32]);                   \
    GLOAD_LDS16(b_src0 + (k0), &Bf[buf][(w*32     )*32]);                  \
    GLOAD_LDS16(b_src1 + (k0), &Bf[buf][(w*32 + 16)*32]);                  \
  }while(0)

  STAGE(0, 0);
  __syncthreads();

  f32x4 acc[2][4] = {};
  const int arow0 = wm*32 + rowL;
  const int akey  = rowL & 7;
  const int bkeyR = (rowL ^ (rowL >> 2)) & 3;

  int cur = 0;
  for(int step = 0; step < 32; step++){
    if(step < 31) STAGE(cur^1, (step+1)*32);
    bf16x8 af[2];
    #pragma unroll
    for(int mf = 0; mf < 2; mf++){
      const int ar = arow0 + mf*16;
      f32x4 x0 = *(const f32x4*)&Af[cur][ar*32 + (((2*kq  ) ^ akey) << 2)];
      f32x4 x1 = *(const f32x4*)&Af[cur][ar*32 + (((2*kq+1) ^ akey) << 2)];
      union { bf16x8 v; unsigned short s[8]; } pk;
      #pragma unroll
      for(int j = 0; j < 4; j++){ pk.s[j] = f32_to_bf16(x0[j]); pk.s[4+j] = f32_to_bf16(x1[j]); }
      af[mf] = pk.v;
    }
    bf16x8 bfr[4];
    #pragma unroll
    for(int nf = 0; nf < 4; nf++){
      const int br = wn*64 + nf*16 + rowL;
      bfr[nf] = *(const bf16x8*)&Bf[cur][br*32 + ((kq ^ bkeyR) << 3)];
    }
    #pragma unroll
    for(int mf = 0; mf < 2; mf++)
      #pragma unroll
      for(int nf = 0; nf < 4; nf++)
        acc[mf][nf] = __builtin_amdgcn_mfma_f32_16x16x32_bf16(af[mf], bfr[nf], acc[mf][nf], 0, 0, 0);
    __syncthreads();
    cur ^= 1;
  }
  #undef STAGE

  #pragma unroll
  for(int mf = 0; mf < 2; mf++){
    #pragma unroll
    for(int nf = 0; nf < 4; nf++){
      const int col = wn*64 + nf*16 + rowL;
      const float bv = b1[col];
      #pragma unroll
      for(int r = 0; r < 4; r++){
        const int gr = row0 + wm*32 + mf*16 + kq*4 + r;
        if(gr < NN) h1[(size_t)gr*128 + col] = f32_to_bf16(fmaxf(acc[mf][nf][r] + bv, 0.f));
      }
    }
  }
}

// ---------------- shared UV phase: [u|v] = h @ Wg1 from swizzled LDS (h AND Wg1T) ----------------

__device__ __forceinline__ void uv_phase2(
    const unsigned short* hs, const unsigned short* wgl, int row0, int wave, int lane,
    const float* __restrict__ bg1,
    unsigned short* __restrict__ UH, float* __restrict__ Vf)
{
  const int rowL = lane & 15, kq = lane >> 4;
  const int r = wave*16 + rowL;
  f32x4 acc[16] = {};
  #pragma unroll
  for(int ks = 0; ks < 4; ks++){
    const int kc = ks*4 + kq;
    bf16x8 a = *(const bf16x8*)&hs[r*128 + ((kc ^ (r & 15)) << 3)];
    #pragma unroll
    for(int nt = 0; nt < 16; nt++){
      bf16x8 b = *(const bf16x8*)&wgl[(nt*16 + rowL)*128 + ((kc ^ rowL) << 3)];
      acc[nt] = __builtin_amdgcn_mfma_f32_16x16x32_bf16(a, b, acc[nt], 0, 0, 0);
    }
  }
  #pragma unroll
  for(int nt = 0; nt < 16; nt++){
    const int col = nt*16 + rowL;
    #pragma unroll
    for(int rr = 0; rr < 4; rr++){
      const int gr = row0 + wave*16 + kq*4 + rr;
      if(gr < NN){
        if(col < 128) UH[(size_t)gr*256 + col] = f32_to_bf16(acc[nt][rr]);
        else          Vf[(size_t)gr*128 + col - 128] = acc[nt][rr] + bg1[col - 128];
      }
    }
  }
}

// ---------------- k_uvA: h = relu(h1@W2T + b2); writes UH=[u|h] bf16, Vf=v+bg1 ----------------

__global__ __launch_bounds__(256) void k_uvA(
    const unsigned short* __restrict__ h1, const unsigned short* __restrict__ W2T,
    const float* __restrict__ b2, const unsigned short* __restrict__ Wg1T,
    const float* __restrict__ bg1, unsigned short* __restrict__ UH,
    float* __restrict__ Vf)
{
  __shared__ __attribute__((aligned(16))) unsigned short hs[64*128];
  __shared__ __attribute__((aligned(16))) unsigned short wgl[256*128];
  const int t = threadIdx.x, wave = t >> 6, lane = t & 63;
  const int rowL = lane & 15, kq = lane >> 4;
  const int row0 = blockIdx.x*64;

  bf16x8 wreg[16];
  #pragma unroll
  for(int i = 0; i < 16; i++)
    wreg[i] = *(const bf16x8*)(Wg1T + (i*256 + t)*8);

  int ar = row0 + wave*16 + rowL; if(ar >= NN) ar = NN-1;
  f32x4 acc[8] = {};
  #pragma unroll
  for(int ks = 0; ks < 4; ks++){
    bf16x8 a = *(const bf16x8*)(h1 + (size_t)ar*128 + ks*32 + kq*8);
    #pragma unroll
    for(int nt = 0; nt < 8; nt++){
      bf16x8 b = *(const bf16x8*)(W2T + (nt*16 + rowL)*128 + ks*32 + kq*8);
      acc[nt] = __builtin_amdgcn_mfma_f32_16x16x32_bf16(a, b, acc[nt], 0, 0, 0);
    }
  }
  #pragma unroll
  for(int nt = 0; nt < 8; nt++){
    const int col = nt*16 + rowL;
    const float bv = b2[col];
    #pragma unroll
    for(int r = 0; r < 4; r++){
      const int rw = wave*16 + kq*4 + r;
      const unsigned short hv = f32_to_bf16(fmaxf(acc[nt][r] + bv, 0.f));
      hs[rw*128 + (((col >> 3) ^ (rw & 15)) << 3) + (col & 7)] = hv;
    }
  }
  #pragma unroll
  for(int i = 0; i < 16; i++){
    const int idx = i*256 + t, row = idx >> 4, c = idx & 15;
    *(bf16x8*)&wgl[row*128 + ((c ^ (row & 15)) << 3)] = wreg[i];
  }
  __syncthreads();
  {
    const int r = t >> 2, gr = row0 + r;
    if(gr < NN){
      #pragma unroll
      for(int j8 = 0; j8 < 4; j8++){
        const int chunk = (t & 3)*4 + j8;
        bf16x8 v = *(const bf16x8*)&hs[r*128 + ((chunk ^ (r & 15)) << 3)];
        *(bf16x8*)&UH[(size_t)gr*256 + 128 + chunk*8] = v;
      }
    }
  }
  uv_phase2(hs, wgl, row0, wave, lane, bg1, UH, Vf);
}

// ---------------- k_uvB: input h f32 (agg output); writes UH=[u|h] bf16, Vf=v+bg1 ----------------

__global__ __launch_bounds__(256) void k_uvB(
    const float* __restrict__ hf, const unsigned short* __restrict__ Wg1T,
    const float* __restrict__ bg1, unsigned short* __restrict__ UH,
    float* __restrict__ Vf)
{
  __shared__ __attribute__((aligned(16))) unsigned short hs[64*128];
  __shared__ __attribute__((aligned(16))) unsigned short wgl[256*128];
  const int t = threadIdx.x, wave = t >> 6, lane = t & 63;
  const int row0 = blockIdx.x*64;

  bf16x8 wreg[16];
  #pragma unroll
  for(int i = 0; i < 16; i++)
    wreg[i] = *(const bf16x8*)(Wg1T + (i*256 + t)*8);

  {
    const int r = t >> 2, gr0 = row0 + r;
    const int gr = (gr0 < NN) ? gr0 : NN-1;
    const float* p = hf + (size_t)gr*128 + (t & 3)*32;
    #pragma unroll
    for(int j8 = 0; j8 < 4; j8++){
      f32x4 v0 = *(const f32x4*)(p + j8*8);
      f32x4 v1 = *(const f32x4*)(p + j8*8 + 4);
      union { bf16x8 v; unsigned short s[8]; } pk;
      #pragma unroll
      for(int j = 0; j < 4; j++){ pk.s[j] = f32_to_bf16(v0[j]); pk.s[4+j] = f32_to_bf16(v1[j]); }
      const int chunk = (t & 3)*4 + j8;
      *(bf16x8*)&hs[r*128 + ((chunk ^ (r & 15)) << 3)] = pk.v;
      if(gr0 < NN) *(bf16x8*)&UH[(size_t)gr0*256 + 128 + chunk*8] = pk.v;
    }
  }
  #pragma unroll
  for(int i = 0; i < 16; i++){
    const int idx = i*256 + t, row = idx >> 4, c = idx & 15;
    *(bf16x8*)&wgl[row*128 + ((c ^ (row & 15)) << 3)] = wreg[i];
  }
  __syncthreads();
  uv_phase2(hs, wgl, row0, wave, lane & 63, bg1, UH, Vf);
}

// ---------------- fused gate + aggregation, CSR order, one wave per dst node ----------------
// gate: 8 edges/iter (2 per 16-lane group in flight), DPP row reduction,
// depth-1 pair prefetch (= 2x outstanding gather bytes), packed {c,src} metadata.

__global__ __launch_bounds__(256) void k_gate_agg(
    const unsigned short* __restrict__ UH, const float* __restrict__ Vf,
    const int* __restrict__ row_ptr, const float2* __restrict__ scp,
    const float* __restrict__ Wg2, const float* __restrict__ bg2p,
    float* __restrict__ out_f32)
{
  __shared__ float2 ws_s[4][64];
  const int wv = threadIdx.x >> 6, lane = threadIdx.x & 63;
  const int gw = blockIdx.x*4 + wv;
  if(gw >= NN) return;
  const int eq = lane >> 4, li = lane & 15;

  f32x4 va = *(const f32x4*)(Vf + (size_t)gw*128 + li*8);
  f32x4 vb = *(const f32x4*)(Vf + (size_t)gw*128 + li*8 + 4);
  f32x4 wa = *(const f32x4*)(Wg2 + li*8);
  f32x4 wb = *(const f32x4*)(Wg2 + li*8 + 4);
  const float vch[8]  = {va[0],va[1],va[2],va[3],vb[0],vb[1],vb[2],vb[3]};
  const float w2ch[8] = {wa[0],wa[1],wa[2],wa[3],wb[0],wb[1],wb[2],wb[3]};
  const float bg2v = bg2p[0];

  const int beg = row_ptr[gw], end = row_ptr[gw+1];
  float a0 = 0.f, a1 = 0.f, wsum = 0.f;

  for(int base = beg; base < end; base += 64){
    const int nb = min(64, end - base);

    // ---- gate: 8 edges/iter, 2 edges per group, depth-1 pair prefetch ----
    float2 sc_c0, sc_c1; bf16x8 u_c0, u_c1;
    {
      const int i0 = (eq     < nb) ? eq     : 0;
      const int i1 = (4 + eq < nb) ? 4 + eq : 0;
      sc_c0 = scp[base + i0]; sc_c1 = scp[base + i1];
      u_c0 = *(const bf16x8*)&UH[(uint32_t)__float_as_int(sc_c0.y)*256u + li*8];
      u_c1 = *(const bf16x8*)&UH[(uint32_t)__float_as_int(sc_c1.y)*256u + li*8];
    }
    for(int q = 0; q < nb; q += 8){
      float2 sc_n0 = sc_c0, sc_n1 = sc_c1; bf16x8 u_n0 = u_c0, u_n1 = u_c1;
      if(q + 8 < nb){
        const int i0 = (q + 8  + eq < nb) ? q + 8  + eq : 0;
        const int i1 = (q + 12 + eq < nb) ? q + 12 + eq : 0;
        sc_n0 = scp[base + i0]; sc_n1 = scp[base + i1];
        u_n0 = *(const bf16x8*)&UH[(uint32_t)__float_as_int(sc_n0.y)*256u + li*8];
        u_n1 = *(const bf16x8*)&UH[(uint32_t)__float_as_int(sc_n1.y)*256u + li*8];
      }
      { // edge A: idx = q + eq
        union { bf16x8 v; uint32_t u32[4]; } uu; uu.v = u_c0;
        float tacc = 0.f;
        #pragma unroll
        for(int p = 0; p < 4; p++){
          const uint32_t w2b = uu.u32[p];
          tacc += fmaxf(bf16lo_to_f32(w2b) + vch[2*p],   0.f) * w2ch[2*p];
          tacc += fmaxf(bf16hi_to_f32(w2b) + vch[2*p+1], 0.f) * w2ch[2*p+1];
        }
        tacc = DPP_ADD(tacc, 0xB1);
        tacc = DPP_ADD(tacc, 0x4E);
        tacc = DPP_ADD(tacc, 0x141);
        tacc = DPP_ADD(tacc, 0x140);
        const float g = 1.f/(1.f + __expf(-(tacc + bg2v)));
        const int idx = q + eq;
        if(li == 0 && idx < nb) ws_s[wv][idx] = make_float2(sc_c0.x*g, sc_c0.y);
      }
      { // edge B: idx = q + 4 + eq
        union { bf16x8 v; uint32_t u32[4]; } uu; uu.v = u_c1;
        float tacc = 0.f;
        #pragma unroll
        for(int p = 0; p < 4; p++){
          const uint32_t w2b = uu.u32[p];
          tacc += fmaxf(bf16lo_to_f32(w2b) + vch[2*p],   0.f) * w2ch[2*p];
          tacc += fmaxf(bf16hi_to_f32(w2b) + vch[2*p+1], 0.f) * w2ch[2*p+1];
        }
        tacc = DPP_ADD(tacc, 0xB1);
        tacc = DPP_ADD(tacc, 0x4E);
        tacc = DPP_ADD(tacc, 0x141);
        tacc = DPP_ADD(tacc, 0x140);
        const float g = 1.f/(1.f + __expf(-(tacc + bg2v)));
        const int idx = q + 4 + eq;
        if(li == 0 && idx < nb) ws_s[wv][idx] = make_float2(sc_c1.x*g, sc_c1.y);
      }
      sc_c0 = sc_n0; sc_c1 = sc_n1; u_c0 = u_n0; u_c1 = u_n1;
    }

    // ---- aggregate (same-wave LDS producer/consumer; no barrier needed) ----
    #pragma unroll 8
    for(int j = 0; j < nb; j++){
      const float2 p = ws_s[wv][j];
      const float w  = p.x;
      const uint32_t s = (uint32_t)__float_as_int(p.y);
      const uint32_t hw = *(const uint32_t*)&UH[s*256u + 128u + lane*2];
      a0 += w*bf16lo_to_f32(hw);
      a1 += w*bf16hi_to_f32(hw);
      wsum += w;
    }
  }
  const float inv = 1.f/(wsum + EPSV);
  const size_t o = (size_t)gw*128 + lane*2;
  *(f32x2*)&out_f32[o] = (f32x2){a0*inv, a1*inv};
}

// ---------------- launch ----------------

extern "C" void kernel_launch(void* const* d_in, const int* in_sizes, int n_in,
                              void* d_out, int out_size, void* d_ws, size_t ws_size,
                              hipStream_t stream) {
  (void)in_sizes; (void)n_in; (void)out_size; (void)ws_size;
  const float* X      = (const float*)d_in[0];
  const int*   src    = (const int*)d_in[1];
  const int*   dst    = (const int*)d_in[2];
  const float* base_w = (const float*)d_in[3];
  const float* W1     = (const float*)d_in[4];
  const float* b1     = (const float*)d_in[5];
  const float* W2     = (const float*)d_in[6];
  const float* b2     = (const float*)d_in[7];
  const float* Wg1    = (const float*)d_in[8];
  const float* bg1    = (const float*)d_in[9];
  const float* Wg2    = (const float*)d_in[10];
  const float* bg2    = (const float*)d_in[11];
  const float* rho    = (const float*)d_in[12];

  char* ws = (char*)d_ws;
  size_t off = 0;
  auto alloc = [&](size_t bytes)->char*{ char* p = ws + off; off += (bytes + 255) & ~(size_t)255; return p; };
  unsigned short* W1T      = (unsigned short*)alloc((size_t)1024*128*2);
  unsigned short* W2T      = (unsigned short*)alloc((size_t)128*128*2);
  unsigned short* Wg1T     = (unsigned short*)alloc((size_t)256*128*2);
  int*            rank     = (int*)alloc((size_t)EE*4);
  float2*         scp      = (float2*)alloc((size_t)EE*8);
  int*            row_ptr  = (int*)alloc((size_t)(NN+1)*4);
  int*            counts   = (int*)alloc((size_t)NN*4);
  int*            lexcl    = (int*)alloc((size_t)NN*4);
  int*            bsum     = (int*)alloc((size_t)256*4);
  int*            bexcl    = (int*)alloc((size_t)256*4);
  unsigned short* h1       = (unsigned short*)alloc((size_t)NN*128*2);
  unsigned short* UH       = (unsigned short*)alloc((size_t)NN*256*2);
  float*          Vf       = (float*)alloc((size_t)NN*128*4);
  float*          hf_B     = (float*)alloc((size_t)NN*128*4);

  hipMemsetAsync(counts, 0, (size_t)NN*4, stream);
  k_prep_all<<<704, 256, 0, stream>>>(W1, W2, Wg1, W1T, W2T, Wg1T);
  k_hist<<<EE/256, 256, 0, stream>>>(dst, counts, rank);
  k_scan1<<<SCAN_BLKS, 256, 0, stream>>>(counts, lexcl, bsum);
  k_scan2<<<1, 256, 0, stream>>>(bsum, bexcl, row_ptr);
  k_scan3<<<SCAN_BLKS, 256, 0, stream>>>(lexcl, bexcl, row_ptr);
  k_fill<<<EE/256, 256, 0, stream>>>(src, dst, base_w, rho, row_ptr, rank, scp);

  k_enc1<<<782, 256, 0, stream>>>(X, W1T, b1, h1);

  // layer 1
  k_uvA<<<782, 256, 0, stream>>>(h1, W2T, b2, Wg1T, bg1, UH, Vf);
  k_gate_agg<<<12500, 256, 0, stream>>>(UH, Vf, row_ptr, scp, Wg2, bg2, hf_B);
  // layer 2
  k_uvB<<<782, 256, 0, stream>>>(hf_B, Wg1T, bg1, UH, Vf);
  k_gate_agg<<<12500, 256, 0, stream>>>(UH, Vf, row_ptr, scp, Wg2, bg2, (float*)d_out);
}